// Round 15
// baseline (963.811 us; speedup 1.0000x reference)
//
#include <hip/hip_runtime.h>

typedef unsigned short u16;
typedef unsigned int u32;

#define N_NODES 20000
#define N_EDGES 320000
#define FEAT 100
#define XPAD 112   // padded cols for bf16 node mirrors / P / Q / agg (14 x 16B rows)
#define N_RULES 64
#define T_RULE 50
#define H_RNN 256
#define RULE_NUMS 16
#define NTN_OUT 200
#define SCAN_B 79  // ceil(20000/256)
#define NPB 16     // nodes per k_msgagg2 block

typedef __attribute__((ext_vector_type(8))) short short8;
typedef __attribute__((ext_vector_type(4))) float f32x4;

__device__ __forceinline__ u16 f2bu(float f) {
  u32 u = __float_as_uint(f);
  u32 r = (u + 0x7fffu + ((u >> 16) & 1u)) >> 16;   // RNE
  return (u16)r;
}
__device__ __forceinline__ float bu2f(u16 u) {
  return __uint_as_float(((u32)u) << 16);
}
__device__ __forceinline__ u32 pk2(float a, float b) {
  return (u32)f2bu(a) | ((u32)f2bu(b) << 16);
}

__device__ __forceinline__ void lds_st16(void* base, int byteOff, uint4 v) {
  *(uint4*)((char*)base + byteOff) = v;
}
__device__ __forceinline__ short8 lds_ld16(const void* base, int byteOff) {
  return *(const short8*)((const char*)base + byteOff);
}

// XOR swizzle: rows of 256B (128 bf16), flip bits 4..6 by row&7 (G4 / T2)
#define SWZ(row, kByte) (((((row) << 8) + (kByte))) ^ (((row) & 7) << 4))

// H-state LDS swizzle (rows of 512B = 256 bf16): chunk' = (chunk + 5*row) & 31
__device__ __forceinline__ int hs_off(int row, int chunk) {
  return (row << 9) | (((chunk + row * 5) & 31) << 4);
}

__device__ __forceinline__ float tanh_fast(float x) {
  const float e = __expf(2.f * x);
  return 1.f - 2.f / (e + 1.f);
}

// ---------------------------------------------------------------- prep: bf16 mirrors
__global__ void k_prep(const float* __restrict__ nf0, const float* __restrict__ nf1,
                       u16* __restrict__ xb0, u16* __restrict__ xb1) {
  const int total = N_NODES * XPAD;
  for (int i = blockIdx.x * blockDim.x + threadIdx.x; i < total;
       i += gridDim.x * blockDim.x) {
    const int n = i / XPAD;
    const int c = i - n * XPAD;
    const float v0 = (c < FEAT) ? nf0[(size_t)n * FEAT + c] : 0.f;
    const float v1 = (c < FEAT) ? nf1[(size_t)n * FEAT + c] : 0.f;
    xb0[i] = f2bu(v0);
    xb1[i] = f2bu(v1);
  }
}

// ---------------------------------------------------------------- W -> bf16 [3][128][128]
__global__ void k_wprep(const float* __restrict__ linW, u16* __restrict__ Wb) {
  const int idx = blockIdx.x * blockDim.x + threadIdx.x;   // < 3*128*128
  if (idx >= 3 * 128 * 128) return;
  const int c = idx >> 14;
  const int rem = idx & 16383;
  const int r = rem >> 7;
  const int k = rem & 127;
  u16 v = 0;
  if (r < FEAT && k < FEAT) v = f2bu(linW[(size_t)r * 300 + c * 100 + k]);
  Wb[idx] = v;
}

// square [100][100] fp32 -> [128][128] bf16 zero-padded
__global__ void k_wprep_sq(const float* __restrict__ W, u16* __restrict__ Wb) {
  const int idx = blockIdx.x * blockDim.x + threadIdx.x;   // < 128*128
  if (idx >= 128 * 128) return;
  const int r = idx >> 7;
  const int k = idx & 127;
  u16 v = 0;
  if (r < FEAT && k < FEAT) v = f2bu(W[(size_t)r * FEAT + k]);
  Wb[idx] = v;
}

// ---------------------------------------------------------------- CSR build (both graphs)
__global__ void k_count2(const int* __restrict__ d0, const int* __restrict__ d1,
                         int* __restrict__ cnt) {
  const int e = blockIdx.x * blockDim.x + threadIdx.x;
  const int* d = blockIdx.y ? d1 : d0;
  if (e < N_EDGES) atomicAdd(&cnt[blockIdx.y * N_NODES + d[e]], 1);
}

__global__ __launch_bounds__(256) void k_scan1(const int* __restrict__ cnt,
                                               int* __restrict__ off,
                                               int* __restrict__ bsum) {
  __shared__ int buf[256];
  const int g = blockIdx.y, b = blockIdx.x, tid = threadIdx.x;
  const int i = b * 256 + tid;
  const int v = (i < N_NODES) ? cnt[g * N_NODES + i] : 0;
  buf[tid] = v;
  __syncthreads();
  for (int ofs = 1; ofs < 256; ofs <<= 1) {
    const int t = (tid >= ofs) ? buf[tid - ofs] : 0;
    __syncthreads();
    buf[tid] += t;
    __syncthreads();
  }
  if (i < N_NODES) off[g * (N_NODES + 1) + i] = buf[tid] - v;  // excl within block
  if (tid == 255) bsum[g * SCAN_B + b] = buf[255];
}

__global__ __launch_bounds__(128) void k_scan2(int* __restrict__ bsum) {
  __shared__ int s[128];
  const int g = blockIdx.y, tid = threadIdx.x;
  const int v = (tid < SCAN_B) ? bsum[g * SCAN_B + tid] : 0;
  s[tid] = v;
  __syncthreads();
  for (int ofs = 1; ofs < 128; ofs <<= 1) {
    const int t = (tid >= ofs) ? s[tid - ofs] : 0;
    __syncthreads();
    s[tid] += t;
    __syncthreads();
  }
  if (tid < SCAN_B) bsum[g * SCAN_B + tid] = s[tid] - v;  // exclusive
}

__global__ __launch_bounds__(256) void k_scan3(const int* __restrict__ bsum,
                                               int* __restrict__ off,
                                               int* __restrict__ cursor) {
  const int g = blockIdx.y, b = blockIdx.x, tid = threadIdx.x;
  const int i = b * 256 + tid;
  if (i < N_NODES) {
    const int o = off[g * (N_NODES + 1) + i] + bsum[g * SCAN_B + b];
    off[g * (N_NODES + 1) + i] = o;
    cursor[g * N_NODES + i] = o;
  }
  if (i == N_NODES) off[g * (N_NODES + 1) + N_NODES] = N_EDGES;
}

// per CSR slot: elist[pos]=edge id, spos[pos]=src node, dpos[pos]=dst node
__global__ void k_scatter2(const int* __restrict__ s0, const int* __restrict__ d0,
                           const int* __restrict__ s1, const int* __restrict__ d1,
                           int* __restrict__ cursor,
                           int* __restrict__ el0, int* __restrict__ el1,
                           int* __restrict__ sp0, int* __restrict__ sp1,
                           int* __restrict__ dp0, int* __restrict__ dp1) {
  const int e = blockIdx.x * blockDim.x + threadIdx.x;
  const int g = blockIdx.y;
  const int* d = g ? d1 : d0;
  const int* s = g ? s1 : s0;
  if (e < N_EDGES) {
    const int dn = d[e];
    const int pos = atomicAdd(&cursor[g * N_NODES + dn], 1);
    (g ? el1 : el0)[pos] = e;
    (g ? sp1 : sp0)[pos] = s[e];
    (g ? dp1 : dp0)[pos] = dn;
  }
}

// ---------------------------------------------------------------- RNN input-GEMM
// U layout (transposed for k_rec): U[(t*256 + col)*64 + r],  global row gm = t*64+r
template <int VARIANT>
__global__ __launch_bounds__(256) void k_gemm_u(
    const float* __restrict__ Af, const u16* __restrict__ Ab,
    const float* __restrict__ W, const float* __restrict__ b0,
    const float* __restrict__ b1, float* __restrict__ Uout) {
  __shared__ __align__(16) u16 As[64 * 128];   // 16 KB
  __shared__ __align__(16) u16 Bs[128 * 128];  // 32 KB
  const int tid = threadIdx.x;
  const int lane = tid & 63;
  const int wv = tid >> 6;
  const int l15 = lane & 15;
  const int lhi = lane >> 4;
  const int mb = blockIdx.x * 64;
  const int nb = blockIdx.y * 128;
  const int rb = (wv >> 1) * 32;
  const int cb = (wv & 1) * 64;
  constexpr int KV = VARIANT ? 256 : 100;       // valid K
  constexpr int NPH = VARIANT ? 2 : 1;          // 128-wide K phases

  f32x4 acc[2][4];
  const f32x4 z4 = {0.f, 0.f, 0.f, 0.f};
#pragma unroll
  for (int i = 0; i < 2; ++i)
#pragma unroll
    for (int j = 0; j < 4; ++j) acc[i][j] = z4;

  for (int kc = 0; kc < NPH; ++kc) {
    __syncthreads();
    // ---- stage A (64 rows x 128 local-k)
    {
      const int row = tid >> 2;
      const int k0 = (tid & 3) * 32;
      const int gm = mb + row;
      if (VARIANT == 0) {
        const int r = gm & 63;
        const int t = gm >> 6;
        const float* ar = Af + ((size_t)r * T_RULE + t) * FEAT;
#pragma unroll
        for (int c = 0; c < 4; ++c) {
          const int k = k0 + c * 8;
          uint4 v = {0u, 0u, 0u, 0u};
          if (k + 8 <= KV) {
            const float4 fa = *(const float4*)(ar + k);
            const float4 fb = *(const float4*)(ar + k + 4);
            v.x = pk2(fa.x, fa.y); v.y = pk2(fa.z, fa.w);
            v.z = pk2(fb.x, fb.y); v.w = pk2(fb.z, fb.w);
          } else if (k < KV) {   // k == 96
            const float4 fa = *(const float4*)(ar + k);
            v.x = pk2(fa.x, fa.y); v.y = pk2(fa.z, fa.w);
          }
          lds_st16(As, SWZ(row, k * 2), v);
        }
      } else {
        const uint4* ar = (const uint4*)(Ab + (size_t)gm * 256 + kc * 128 + k0);
#pragma unroll
        for (int c = 0; c < 4; ++c)
          lds_st16(As, SWZ(row, (k0 + c * 8) * 2), ar[c]);
      }
    }
    // ---- stage B (128 N-rows x 128 local-k)
    {
      const int row = tid >> 1;
      const int k0 = (tid & 1) * 64;
      const float* wr = W + (size_t)(nb + row) * KV;
#pragma unroll
      for (int c = 0; c < 8; ++c) {
        const int k = k0 + c * 8;
        const int kg = kc * 128 + k;
        uint4 v = {0u, 0u, 0u, 0u};
        if (kg + 8 <= KV) {
          const float4 fa = *(const float4*)(wr + kg);
          const float4 fb = *(const float4*)(wr + kg + 4);
          v.x = pk2(fa.x, fa.y); v.y = pk2(fa.z, fa.w);
          v.z = pk2(fb.x, fb.y); v.w = pk2(fb.z, fb.w);
        } else if (kg < KV) {
          const float4 fa = *(const float4*)(wr + kg);
          v.x = pk2(fa.x, fa.y); v.y = pk2(fa.z, fa.w);
        }
        lds_st16(Bs, SWZ(row, k * 2), v);
      }
    }
    __syncthreads();
#pragma unroll
    for (int s = 0; s < 4; ++s) {
      const int kByte = s * 64 + lhi * 16;
      short8 af[2], bfr[4];
#pragma unroll
      for (int i = 0; i < 2; ++i)
        af[i] = lds_ld16(As, SWZ(rb + i * 16 + l15, kByte));
#pragma unroll
      for (int j = 0; j < 4; ++j)
        bfr[j] = lds_ld16(Bs, SWZ(cb + j * 16 + l15, kByte));
#pragma unroll
      for (int i = 0; i < 2; ++i)
#pragma unroll
        for (int j = 0; j < 4; ++j)
          acc[i][j] = __builtin_amdgcn_mfma_f32_16x16x32_bf16(af[i], bfr[j],
                                                              acc[i][j], 0, 0, 0);
    }
  }
  // ---- epilogue: + (bih + bhh), transposed float4 store
#pragma unroll
  for (int j = 0; j < 4; ++j) {
    const int col = nb + cb + j * 16 + l15;
    const float bias = b0[col] + b1[col];
#pragma unroll
    for (int i = 0; i < 2; ++i) {
      const int base_m = mb + rb + i * 16 + lhi * 4;
      const int t = base_m >> 6;
      const int r0 = base_m & 63;
      float4 st;
      st.x = acc[i][j][0] + bias; st.y = acc[i][j][1] + bias;
      st.z = acc[i][j][2] + bias; st.w = acc[i][j][3] + bias;
      *(float4*)(Uout + ((size_t)t * 256 + col) * 64 + r0) = st;
    }
  }
}

// ---------------------------------------------------------------- RNN recurrence
template <int WRITE_YS>
__global__ __launch_bounds__(512) void k_rec(
    const float* __restrict__ U, const float* __restrict__ Whh,
    u16* __restrict__ ys, float* __restrict__ hT) {
  __shared__ __align__(16) u16 Hs[16 * 256];   // 8 KB
  const int tid = threadIdx.x;
  const int lane = tid & 63;
  const int wv = tid >> 6;          // 8 waves -> 32 cols each
  const int cbase = wv * 32;
  const int ruleBase = blockIdx.x * 16;
  const int l15 = lane & 15;
  const int lhi = lane >> 4;

  short8 bf[2][8];
#pragma unroll
  for (int jt = 0; jt < 2; ++jt) {
    const int col = cbase + jt * 16 + l15;
    const float* wr = Whh + (size_t)col * 256;
#pragma unroll
    for (int s = 0; s < 8; ++s) {
      const int k0 = s * 32 + lhi * 8;
      const float4 fa = *(const float4*)(wr + k0);
      const float4 fb = *(const float4*)(wr + k0 + 4);
      uint4 v;
      v.x = pk2(fa.x, fa.y); v.y = pk2(fa.z, fa.w);
      v.z = pk2(fb.x, fb.y); v.w = pk2(fb.z, fb.w);
      bf[jt][s] = *(short8*)&v;
    }
  }
  for (int i = tid; i < 16 * 256 / 8; i += 512) {
    const uint4 z = {0u, 0u, 0u, 0u};
    ((uint4*)Hs)[i] = z;
  }
  __syncthreads();

  const int n0 = cbase + l15;
  const int n1 = cbase + 16 + l15;
  const int m0 = lhi * 4;
  float4 Ua0 = *(const float4*)(U + ((size_t)n0) * 64 + m0);
  float4 Ua1 = *(const float4*)(U + ((size_t)n1) * 64 + m0);

  const f32x4 z4 = {0.f, 0.f, 0.f, 0.f};
  float hv[2][4];
  for (int t = 0; t < T_RULE; ++t) {
    const int tn = (t + 1 < T_RULE) ? t + 1 : t;
    const float4 Ub0 = *(const float4*)(U + ((size_t)tn * 256 + n0) * 64 + m0);
    const float4 Ub1 = *(const float4*)(U + ((size_t)tn * 256 + n1) * 64 + m0);
    f32x4 acc[2] = {z4, z4};
#pragma unroll
    for (int s = 0; s < 8; ++s) {
      const short8 af = lds_ld16(Hs, hs_off(l15, s * 4 + lhi));
      acc[0] = __builtin_amdgcn_mfma_f32_16x16x32_bf16(af, bf[0][s], acc[0], 0, 0, 0);
      acc[1] = __builtin_amdgcn_mfma_f32_16x16x32_bf16(af, bf[1][s], acc[1], 0, 0, 0);
    }
    const float ua0[4] = {Ua0.x, Ua0.y, Ua0.z, Ua0.w};
    const float ua1[4] = {Ua1.x, Ua1.y, Ua1.z, Ua1.w};
#pragma unroll
    for (int q = 0; q < 4; ++q) {
      hv[0][q] = tanh_fast(ua0[q] + acc[0][q]);
      hv[1][q] = tanh_fast(ua1[q] + acc[1][q]);
    }
    __syncthreads();   // all Hs reads done before overwrite
#pragma unroll
    for (int jt = 0; jt < 2; ++jt) {
      const int n = cbase + jt * 16 + l15;
#pragma unroll
      for (int q = 0; q < 4; ++q) {
        const int m = lhi * 4 + q;
        const u16 hb = f2bu(hv[jt][q]);
        *(u16*)((char*)Hs + (hs_off(m, n >> 3) + ((n & 7) << 1))) = hb;
        if (WRITE_YS)
          ys[(((size_t)t * 64 + ruleBase + m) << 8) + n] = hb;
      }
    }
    Ua0 = Ub0; Ua1 = Ub1;
    __syncthreads();
  }
  if (!WRITE_YS) {
#pragma unroll
    for (int jt = 0; jt < 2; ++jt) {
      const int n = cbase + jt * 16 + l15;
#pragma unroll
      for (int q = 0; q < 4; ++q) {
        const int m = lhi * 4 + q;
        hT[((size_t)(ruleBase + m) << 8) + n] = hv[jt][q];
      }
    }
  }
}

// ---------------------------------------------------------------- rule linear
__global__ __launch_bounds__(128) void k_rulelin(
    const float* __restrict__ hT, const float* __restrict__ rlW,
    const float* __restrict__ rlb, float* __restrict__ emb) {
  __shared__ __align__(16) float hs[H_RNN];
  const int b = blockIdx.x;
  const int tid = threadIdx.x;
  for (int i = tid; i < H_RNN / 4; i += 128)
    ((float4*)hs)[i] = ((const float4*)(hT + (size_t)b * H_RNN))[i];
  __syncthreads();
  if (tid < FEAT) {
    float acc = rlb[tid];
    const float4* w = (const float4*)(rlW + (size_t)tid * H_RNN);
    const float4* hv = (const float4*)hs;
#pragma unroll 8
    for (int k = 0; k < 64; ++k) {
      const float4 a = w[k], x = hv[k];
      acc += a.x * x.x + a.y * x.y + a.z * x.z + a.w * x.w;
    }
    emb[(size_t)b * FEAT + tid] = acc;
  }
}

// ---------------------------------------------------------------- rule ranker
__global__ __launch_bounds__(128) void k_ranker(
    const float* __restrict__ emb,
    const float* __restrict__ W1, const float* __restrict__ b1,
    const float* __restrict__ W2, const float* __restrict__ b2,
    const float* __restrict__ W3, const float* __restrict__ b3,
    float* __restrict__ scores) {
  __shared__ float eb[FEAT];
  __shared__ float h1s[128];
  __shared__ float h2s[64];
  const int r = blockIdx.x;
  const int tid = threadIdx.x;
  if (tid < FEAT) eb[tid] = emb[(size_t)r * FEAT + tid];
  __syncthreads();
  {
    float acc = b1[tid];
    const float* w = W1 + (size_t)tid * FEAT;
    for (int k = 0; k < FEAT; ++k) acc += w[k] * eb[k];
    h1s[tid] = acc > 0.f ? acc : 0.f;
  }
  __syncthreads();
  if (tid < 64) {
    float acc = b2[tid];
    const float* w = W2 + (size_t)tid * 128;
    for (int k = 0; k < 128; ++k) acc += w[k] * h1s[k];
    h2s[tid] = acc > 0.f ? acc : 0.f;
  }
  __syncthreads();
  if (tid == 0) {
    float acc = b3[0];
    for (int k = 0; k < 64; ++k) acc += W3[k] * h2s[k];
    scores[r] = acc;   // sigmoid omitted: monotonic, ranking preserved
  }
}

__global__ void k_topk(const float* __restrict__ scores, int* __restrict__ topidx) {
  if (threadIdx.x == 0 && blockIdx.x == 0) {
    float s[N_RULES];
    for (int i = 0; i < N_RULES; ++i) s[i] = scores[i];
    for (int t = 0; t < RULE_NUMS; ++t) {
      int best = 0;
      float bv = s[0];
      for (int i = 1; i < N_RULES; ++i)
        if (s[i] > bv) { bv = s[i]; best = i; }
      topidx[t] = best;
      s[best] = -1e30f;
    }
  }
}

// ---------------------------------------------------------------- P/Q node GEMM (both graphs)
// grid: (157, 2 = P|Q, 2 = graph)
__global__ __launch_bounds__(256) void k_nodegemm(
    const u16* __restrict__ xbA, const u16* __restrict__ xbB,
    const u16* __restrict__ Wb, const float* __restrict__ linB,
    u16* __restrict__ PA, u16* __restrict__ QA,
    u16* __restrict__ PB, u16* __restrict__ QB) {
  __shared__ __align__(16) u16 As[128 * 128];
  __shared__ __align__(16) u16 Bs[128 * 128];
  const int tid = threadIdx.x;
  const int lane = tid & 63;
  const int wv = tid >> 6;
  const int l15 = lane & 15;
  const int lhi = lane >> 4;
  const int n0 = blockIdx.x * 128;
  const int p = blockIdx.y;
  const int gph = blockIdx.z;
  const u16* xb = gph ? xbB : xbA;
  u16* Out = gph ? (p ? QB : PB) : (p ? QA : PA);
  const int rStage = tid >> 1;
  const int hf = tid & 1;
  const int rb = (wv >> 1) * 64;
  const int cb = (wv & 1) * 64;

  {
    const int node = n0 + rStage;
    const bool ok = node < N_NODES;
    const uint4* xr = (const uint4*)(xb + (size_t)node * XPAD);
#pragma unroll
    for (int q = 0; q < 8; ++q) {
      const int cc = hf * 8 + q;
      uint4 v = {0u, 0u, 0u, 0u};
      if (ok && cc < 14) v = xr[cc];
      lds_st16(As, SWZ(rStage, cc * 16), v);
    }
  }
  {
    const uint4* wr = (const uint4*)(Wb + (size_t)(p ? 2 : 0) * 16384 +
                                     (size_t)rStage * 128);
#pragma unroll
    for (int q = 0; q < 8; ++q) {
      const int cc = hf * 8 + q;
      lds_st16(Bs, SWZ(rStage, cc * 16), wr[cc]);
    }
  }
  __syncthreads();

  f32x4 acc[4][4];
  const f32x4 z4 = {0.f, 0.f, 0.f, 0.f};
#pragma unroll
  for (int i = 0; i < 4; ++i)
#pragma unroll
    for (int j = 0; j < 4; ++j) acc[i][j] = z4;
#pragma unroll
  for (int s = 0; s < 4; ++s) {
    const int kByte = s * 64 + lhi * 16;
    short8 af[4], bfr[4];
#pragma unroll
    for (int i = 0; i < 4; ++i) {
      af[i] = lds_ld16(As, SWZ(rb + i * 16 + l15, kByte));
      bfr[i] = lds_ld16(Bs, SWZ(cb + i * 16 + l15, kByte));
    }
#pragma unroll
    for (int i = 0; i < 4; ++i)
#pragma unroll
      for (int j = 0; j < 4; ++j)
        acc[i][j] = __builtin_amdgcn_mfma_f32_16x16x32_bf16(af[i], bfr[j],
                                                            acc[i][j], 0, 0, 0);
  }
#pragma unroll
  for (int j = 0; j < 4; ++j) {
    const int col = cb + j * 16 + l15;
    if (col >= XPAD) continue;
    const bool valid = col < FEAT;
    const float bias = (valid && !p) ? linB[col] : 0.f;
#pragma unroll
    for (int i = 0; i < 4; ++i) {
      const int row0 = rb + i * 16 + lhi * 4;
#pragma unroll
      for (int q = 0; q < 4; ++q) {
        const int node = n0 + row0 + q;
        if (node < N_NODES)
          Out[(size_t)node * XPAD + col] = valid ? f2bu(acc[i][j][q] + bias) : (u16)0;
      }
    }
  }
}

// ---------------------------------------------------------------- fused message+aggregate v2 (both graphs)
// grid: (1250, 2 = graph). Block owns NPB=16 whole nodes of its graph.
__global__ __launch_bounds__(256, 4) void k_msgagg2(
    const float* __restrict__ efA, const float* __restrict__ efB,
    const u16* __restrict__ Wb,
    const int* __restrict__ elA, const int* __restrict__ elB,
    const int* __restrict__ spA, const int* __restrict__ spB,
    const int* __restrict__ dpA, const int* __restrict__ dpB,
    const int* __restrict__ offAll,
    const u16* __restrict__ PA, const u16* __restrict__ QA,
    const u16* __restrict__ PB, const u16* __restrict__ QB,
    const u16* __restrict__ xbA, const u16* __restrict__ xbB,
    u16* __restrict__ aggA, u16* __restrict__ aggB) {
  __shared__ __align__(16) u16 As[64 * 128];   // 16 KB
  const int gph = blockIdx.y;
  const float* ef = gph ? efB : efA;
  const int* elist = gph ? elB : elA;
  const int* spos = gph ? spB : spA;
  const int* dpos = gph ? dpB : dpA;
  const int* off = offAll + gph * (N_NODES + 1);
  const u16* Pb = gph ? PB : PA;
  const u16* Qb = gph ? QB : QA;
  const u16* xb = gph ? xbB : xbA;
  u16* aggb = gph ? aggB : aggA;

  const int tid = threadIdx.x;
  const int lane = tid & 63;
  const int wv = tid >> 6;
  const int l15 = lane & 15;
  const int lhi = lane >> 4;
  const int nb0 = blockIdx.x * NPB;
  const int rr = tid >> 2;          // tile row 0..63
  const int t4 = tid & 3;
  const int cb = wv * 32;           // wave: all 64 rows x cols cb..cb+31
  const f32x4 z4 = {0.f, 0.f, 0.f, 0.f};

  const int p0 = off[nb0];
  const int pEnd = off[nb0 + NPB];

  // segsum mapping: thread = (local node sl, 8-col chunk sc8); 16x16 = 256
  const int sl = tid >> 4;
  const int sc8 = tid & 15;
  const int myS = off[nb0 + sl];
  const int myE = off[nb0 + sl + 1];
  float a8[8] = {0.f, 0.f, 0.f, 0.f, 0.f, 0.f, 0.f, 0.f};

  // ---- We B-fragments -> registers (2 col-tiles x 4 k-steps = 32 VGPR)
  short8 bf[2][4];
  {
    const u16* wbase = Wb + 16384;  // chunk 1 = We
#pragma unroll
    for (int jt = 0; jt < 2; ++jt) {
      const u16* wr = wbase + (size_t)(cb + jt * 16 + l15) * 128;
#pragma unroll
      for (int s = 0; s < 4; ++s)
        bf[jt][s] = *(const short8*)(wr + s * 32 + lhi * 8);
    }
  }

  for (int base = p0; base < pEnd; base += 64) {
    const int slot = base + rr;
    const bool valid = slot < pEnd;
    // ---- stage A: gather ef rows (400B each, float4-aligned)
    {
      const int e = valid ? elist[slot] : 0;
      const int k0 = t4 * 32;
      const float* ar = ef + (size_t)e * FEAT;
#pragma unroll
      for (int c = 0; c < 4; ++c) {
        const int k = k0 + c * 8;
        uint4 v = {0u, 0u, 0u, 0u};
        if (valid) {
          if (k + 8 <= FEAT) {
            const float4 fa = *(const float4*)(ar + k);
            const float4 fb = *(const float4*)(ar + k + 4);
            v.x = pk2(fa.x, fa.y); v.y = pk2(fa.z, fa.w);
            v.z = pk2(fb.x, fb.y); v.w = pk2(fb.z, fb.w);
          } else if (k < FEAT) {   // k == 96
            const float4 fa = *(const float4*)(ar + k);
            v.x = pk2(fa.x, fa.y); v.y = pk2(fa.z, fa.w);
          }
        }
        lds_st16(As, SWZ(rr, k * 2), v);
      }
    }
    __syncthreads();
    // ---- MFMA: 64x128 tile; wave covers 4 row-tiles x 2 col-tiles
    f32x4 acc[4][2];
#pragma unroll
    for (int i = 0; i < 4; ++i)
#pragma unroll
      for (int j = 0; j < 2; ++j) acc[i][j] = z4;
#pragma unroll
    for (int s = 0; s < 4; ++s) {
      const int kByte = s * 64 + lhi * 16;
      short8 af[4];
#pragma unroll
      for (int i = 0; i < 4; ++i)
        af[i] = lds_ld16(As, SWZ(i * 16 + l15, kByte));
#pragma unroll
      for (int i = 0; i < 4; ++i)
#pragma unroll
        for (int j = 0; j < 2; ++j)
          acc[i][j] = __builtin_amdgcn_mfma_f32_16x16x32_bf16(af[i], bf[j][s],
                                                              acc[i][j], 0, 0, 0);
    }
    __syncthreads();
    // ---- E tile -> LDS (bf16, swizzled; reuse As)
#pragma unroll
    for (int i = 0; i < 4; ++i) {
#pragma unroll
      for (int j = 0; j < 2; ++j) {
        const int col = cb + j * 16 + l15;
#pragma unroll
        for (int q = 0; q < 4; ++q) {
          const int row = i * 16 + lhi * 4 + q;
          *(u16*)((char*)As + (SWZ(row, col * 2))) = f2bu(acc[i][j][q]);
        }
      }
    }
    __syncthreads();
    // ---- row pass: m = relu(E + P[dst] + Q[src]) back into LDS (chunks 0..13)
    {
      const int dn = valid ? dpos[slot] : 0;
      const int sn = valid ? spos[slot] : 0;
#pragma unroll
      for (int c = 0; c < 4; ++c) {
        const int chunk = t4 * 4 + c;
        if (chunk >= 14) break;   // cols 112..127 stay as E (= 0)
        const uint4 p4 = *(const uint4*)(Pb + (size_t)dn * XPAD + chunk * 8);
        const uint4 q4 = *(const uint4*)(Qb + (size_t)sn * XPAD + chunk * 8);
        const short8 ev = lds_ld16(As, SWZ(rr, chunk * 16));
        const uint4 e4 = *(const uint4*)&ev;
        uint4 o;
        float v0 = bu2f((u16)(e4.x & 0xffffu)) + bu2f((u16)(p4.x & 0xffffu)) +
                   bu2f((u16)(q4.x & 0xffffu));
        float v1 = bu2f((u16)(e4.x >> 16)) + bu2f((u16)(p4.x >> 16)) +
                   bu2f((u16)(q4.x >> 16));
        o.x = pk2(v0 > 0.f ? v0 : 0.f, v1 > 0.f ? v1 : 0.f);
        float v2 = bu2f((u16)(e4.y & 0xffffu)) + bu2f((u16)(p4.y & 0xffffu)) +
                   bu2f((u16)(q4.y & 0xffffu));
        float v3 = bu2f((u16)(e4.y >> 16)) + bu2f((u16)(p4.y >> 16)) +
                   bu2f((u16)(q4.y >> 16));
        o.y = pk2(v2 > 0.f ? v2 : 0.f, v3 > 0.f ? v3 : 0.f);
        float v4 = bu2f((u16)(e4.z & 0xffffu)) + bu2f((u16)(p4.z & 0xffffu)) +
                   bu2f((u16)(q4.z & 0xffffu));
        float v5 = bu2f((u16)(e4.z >> 16)) + bu2f((u16)(p4.z >> 16)) +
                   bu2f((u16)(q4.z >> 16));
        o.z = pk2(v4 > 0.f ? v4 : 0.f, v5 > 0.f ? v5 : 0.f);
        float v6 = bu2f((u16)(e4.w & 0xffffu)) + bu2f((u16)(p4.w & 0xffffu)) +
                   bu2f((u16)(q4.w & 0xffffu));
        float v7 = bu2f((u16)(e4.w >> 16)) + bu2f((u16)(p4.w >> 16)) +
                   bu2f((u16)(q4.w >> 16));
        o.w = pk2(v6 > 0.f ? v6 : 0.f, v7 > 0.f ? v7 : 0.f);
        lds_st16(As, SWZ(rr, chunk * 16), o);
      }
    }
    __syncthreads();
    // ---- register segment-sum: thread (sl, sc8) owns node nb0+sl cols sc8*8..+7
    {
      const int gs = myS > base ? myS : base;
      const int ge = myE < base + 64 ? myE : base + 64;
      for (int r = gs; r < ge; ++r) {
        const short8 mv = lds_ld16(As, SWZ(r - base, sc8 * 16));
        const uint4 m4 = *(const uint4*)&mv;
        a8[0] += bu2f((u16)(m4.x & 0xffffu)); a8[1] += bu2f((u16)(m4.x >> 16));
        a8[2] += bu2f((u16)(m4.y & 0xffffu)); a8[3] += bu2f((u16)(m4.y >> 16));
        a8[4] += bu2f((u16)(m4.z & 0xffffu)); a8[5] += bu2f((u16)(m4.z >> 16));
        a8[6] += bu2f((u16)(m4.w & 0xffffu)); a8[7] += bu2f((u16)(m4.w >> 16));
      }
    }
    __syncthreads();   // before next tile overwrites As
  }
  // ---- epilogue: + xb residual, write aggb (bf16); chunks 0..13 cover XPAD
  if (sc8 < 14) {
    const int node = nb0 + sl;
    const uint4 xv = *(const uint4*)(xb + (size_t)node * XPAD + sc8 * 8);
    uint4 o;
    o.x = pk2(a8[0] + bu2f((u16)(xv.x & 0xffffu)),
              a8[1] + bu2f((u16)(xv.x >> 16)));
    o.y = pk2(a8[2] + bu2f((u16)(xv.y & 0xffffu)),
              a8[3] + bu2f((u16)(xv.y >> 16)));
    o.z = pk2(a8[4] + bu2f((u16)(xv.z & 0xffffu)),
              a8[5] + bu2f((u16)(xv.z >> 16)));
    o.w = pk2(a8[6] + bu2f((u16)(xv.w & 0xffffu)),
              a8[7] + bu2f((u16)(xv.w >> 16)));
    *(uint4*)(aggb + (size_t)node * XPAD + sc8 * 8) = o;
  }
}

// ---------------------------------------------------------------- node MLP (both graphs)
// grid: (157, 2 = graph)
__global__ __launch_bounds__(256) void k_mlp(
    const u16* __restrict__ aggA, const u16* __restrict__ aggB,
    const u16* __restrict__ W1b, const float* __restrict__ b1,
    const u16* __restrict__ W2b, const float* __restrict__ b2,
    u16* __restrict__ xbA, u16* __restrict__ xbB) {
  __shared__ __align__(16) u16 As[128 * 128];
  __shared__ __align__(16) u16 Bs[128 * 128];
  const int gph = blockIdx.y;
  const u16* aggb = gph ? aggB : aggA;
  u16* xbout = gph ? xbB : xbA;
  const int tid = threadIdx.x;
  const int lane = tid & 63;
  const int wv = tid >> 6;
  const int l15 = lane & 15;
  const int lhi = lane >> 4;
  const int n0 = blockIdx.x * 128;
  const int rStage = tid >> 1;
  const int hf = tid & 1;
  const int rb = (wv >> 1) * 64;
  const int cb = (wv & 1) * 64;
  const f32x4 z4 = {0.f, 0.f, 0.f, 0.f};

  // ---- stage A: agg rows (pre-padded bf16, straight copies)
  {
    const int node = n0 + rStage;
    const bool ok = node < N_NODES;
    const uint4* xr = (const uint4*)(aggb + (size_t)node * XPAD);
#pragma unroll
    for (int q = 0; q < 8; ++q) {
      const int cc = hf * 8 + q;
      uint4 v = {0u, 0u, 0u, 0u};
      if (ok && cc < 14) v = xr[cc];
      lds_st16(As, SWZ(rStage, cc * 16), v);
    }
  }
  // ---- stage B: W1b
  {
    const uint4* wr = (const uint4*)(W1b + (size_t)rStage * 128);
#pragma unroll
    for (int q = 0; q < 8; ++q) {
      const int cc = hf * 8 + q;
      lds_st16(Bs, SWZ(rStage, cc * 16), wr[cc]);
    }
  }
  __syncthreads();

  f32x4 acc[4][4];
#pragma unroll
  for (int i = 0; i < 4; ++i)
#pragma unroll
    for (int j = 0; j < 4; ++j) acc[i][j] = z4;
#pragma unroll
  for (int s = 0; s < 4; ++s) {
    const int kByte = s * 64 + lhi * 16;
    short8 af[4], bfr[4];
#pragma unroll
    for (int i = 0; i < 4; ++i) {
      af[i] = lds_ld16(As, SWZ(rb + i * 16 + l15, kByte));
      bfr[i] = lds_ld16(Bs, SWZ(cb + i * 16 + l15, kByte));
    }
#pragma unroll
    for (int i = 0; i < 4; ++i)
#pragma unroll
      for (int j = 0; j < 4; ++j)
        acc[i][j] = __builtin_amdgcn_mfma_f32_16x16x32_bf16(af[i], bfr[j],
                                                            acc[i][j], 0, 0, 0);
  }
  __syncthreads();
  // ---- epilogue 1: h = relu(acc + b1) -> As (cols >=100 are 0 automatically)
#pragma unroll
  for (int j = 0; j < 4; ++j) {
    const int col = cb + j * 16 + l15;
    const float bias = (col < FEAT) ? b1[col] : 0.f;
#pragma unroll
    for (int i = 0; i < 4; ++i) {
      const int row0 = rb + i * 16 + lhi * 4;
#pragma unroll
      for (int q = 0; q < 4; ++q) {
        float v = acc[i][j][q] + bias;
        v = v > 0.f ? v : 0.f;
        *(u16*)((char*)As + (SWZ(row0 + q, col * 2))) = f2bu(v);
      }
    }
  }
  // ---- stage B2: W2b
  {
    const uint4* wr = (const uint4*)(W2b + (size_t)rStage * 128);
#pragma unroll
    for (int q = 0; q < 8; ++q) {
      const int cc = hf * 8 + q;
      lds_st16(Bs, SWZ(rStage, cc * 16), wr[cc]);
    }
  }
  __syncthreads();

#pragma unroll
  for (int i = 0; i < 4; ++i)
#pragma unroll
    for (int j = 0; j < 4; ++j) acc[i][j] = z4;
#pragma unroll
  for (int s = 0; s < 4; ++s) {
    const int kByte = s * 64 + lhi * 16;
    short8 af[4], bfr[4];
#pragma unroll
    for (int i = 0; i < 4; ++i) {
      af[i] = lds_ld16(As, SWZ(rb + i * 16 + l15, kByte));
      bfr[i] = lds_ld16(Bs, SWZ(cb + i * 16 + l15, kByte));
    }
#pragma unroll
    for (int i = 0; i < 4; ++i)
#pragma unroll
      for (int j = 0; j < 4; ++j)
        acc[i][j] = __builtin_amdgcn_mfma_f32_16x16x32_bf16(af[i], bfr[j],
                                                            acc[i][j], 0, 0, 0);
  }
  // ---- epilogue 2: out = relu(acc + b2) -> xb (bf16, pads zeroed)
#pragma unroll
  for (int j = 0; j < 4; ++j) {
    const int col = cb + j * 16 + l15;
    if (col >= XPAD) continue;
    const bool valid = col < FEAT;
    const float bias = valid ? b2[col] : 0.f;
#pragma unroll
    for (int i = 0; i < 4; ++i) {
      const int row0 = rb + i * 16 + lhi * 4;
#pragma unroll
      for (int q = 0; q < 4; ++q) {
        const int node = n0 + row0 + q;
        if (node < N_NODES) {
          float v = acc[i][j][q] + bias;
          v = v > 0.f ? v : 0.f;
          xbout[(size_t)node * XPAD + col] = valid ? f2bu(v) : (u16)0;
        }
      }
    }
  }
}

// ---------------------------------------------------------------- global add pool (bf16 in)
__global__ void k_pool(const u16* __restrict__ xb, float* __restrict__ g) {
  const int tid = threadIdx.x;
  if (tid >= FEAT) return;
  float s = 0.f;
  const int n0 = blockIdx.x * 100;
  for (int i = 0; i < 100; ++i) s += bu2f(xb[(size_t)(n0 + i) * XPAD + tid]);
  atomicAdd(&g[tid], s);
}

// ---------------------------------------------------------------- NTN bilinear
__global__ __launch_bounds__(256) void k_ntn(const float* __restrict__ W,
                                             const float* __restrict__ g1,
                                             const float* __restrict__ g2,
                                             float* __restrict__ tp) {
  __shared__ float g2s[FEAT];
  const int i = blockIdx.x;
  const int tid = threadIdx.x;
  if (tid < FEAT) g2s[tid] = g2[tid];
  __syncthreads();
  if (tid < NTN_OUT) {
    const float g1i = g1[i];
    float acc = 0.f;
    const float* wr = W + (size_t)i * FEAT * NTN_OUT + tid;
    for (int jj = 0; jj < FEAT; ++jj) acc += wr[(size_t)jj * NTN_OUT] * g2s[jj];
    atomicAdd(&tp[tid], g1i * acc);
  }
}

// ---------------------------------------------------------------- head
__global__ __launch_bounds__(256) void k_feat(
    const float* __restrict__ tp, const float* __restrict__ gv,
    const float* __restrict__ V, const float* __restrict__ B,
    const float* __restrict__ emb, const int* __restrict__ topidx,
    float* __restrict__ featOut) {
  const int tid = threadIdx.x;
  if (tid < NTN_OUT) {
    float acc = B[tid] + tp[tid];
    const float* vr = V + (size_t)tid * 200;
    for (int k = 0; k < 200; ++k) acc += vr[k] * gv[k];
    featOut[tid] = acc > 0.f ? acc : 0.f;
  }
  for (int i = tid; i < RULE_NUMS * FEAT; i += 256) {
    const int rr = i / FEAT;
    const int cc = i - rr * FEAT;
    featOut[NTN_OUT + i] = emb[(size_t)topidx[rr] * FEAT + cc];
  }
}

__global__ __launch_bounds__(256) void k_fc1(
    const float* __restrict__ feat, const float* __restrict__ W,
    const float* __restrict__ b, float* __restrict__ z1) {
  __shared__ __align__(16) float fs[NTN_OUT + RULE_NUMS * FEAT];
  const int tid = threadIdx.x;
  for (int i = tid; i < 450; i += 256) ((float4*)fs)[i] = ((const float4*)feat)[i];
  __syncthreads();
  const int lane = tid & 63;
  const int wv = tid >> 6;
  const int o = blockIdx.x * 4 + wv;
  float acc = 0.f;
  const float4* w4 = (const float4*)(W + (size_t)o * 1800);
  const float4* f4 = (const float4*)fs;
  for (int k = lane; k < 450; k += 64) {
    const float4 a = w4[k], x = f4[k];
    acc += a.x * x.x + a.y * x.y + a.z * x.z + a.w * x.w;
  }
#pragma unroll
  for (int d = 32; d; d >>= 1) acc += __shfl_down(acc, d);
  if (lane == 0) {
    acc += b[o];
    z1[o] = acc > 0.f ? acc : 0.f;
  }
}

__global__ __launch_bounds__(128) void k_head2(
    const float* __restrict__ z1g, const float* __restrict__ fc2W,
    const float* __restrict__ fc2b, const float* __restrict__ fc3W,
    const float* __restrict__ fc3b, float* __restrict__ out) {
  __shared__ __align__(16) float z1[500];
  __shared__ float z2[FEAT];
  const int tid = threadIdx.x;
  for (int i = tid; i < 125; i += 128) ((float4*)z1)[i] = ((const float4*)z1g)[i];
  __syncthreads();
  if (tid < FEAT) {
    float acc = fc2b[tid];
    const float4* w4 = (const float4*)(fc2W + (size_t)tid * 500);
    const float4* f4 = (const float4*)z1;
#pragma unroll 5
    for (int k = 0; k < 125; ++k) {
      const float4 a = w4[k], x = f4[k];
      acc += a.x * x.x + a.y * x.y + a.z * x.z + a.w * x.w;
    }
    z2[tid] = acc > 0.f ? acc : 0.f;
  }
  __syncthreads();
  if (tid == 0) {
    float acc = fc3b[0];
    for (int k = 0; k < FEAT; ++k) acc += fc3W[k] * z2[k];
    out[0] = 1.f / (1.f + expf(-acc));
  }
}

// ================================================================ launch
extern "C" void kernel_launch(void* const* d_in, const int* in_sizes, int n_in,
                              void* d_out, int out_size, void* d_ws, size_t ws_size,
                              hipStream_t stream) {
  (void)in_sizes; (void)n_in; (void)out_size; (void)ws_size;

  const float* nf[2] = {(const float*)d_in[0], (const float*)d_in[1]};
  const int* ei[2] = {(const int*)d_in[2], (const int*)d_in[3]};
  const float* ef[2] = {(const float*)d_in[4], (const float*)d_in[5]};
  const float* rules = (const float*)d_in[6];
  const float* cw[2][6];
  for (int l = 0; l < 2; ++l)
    for (int k = 0; k < 6; ++k) cw[l][k] = (const float*)d_in[7 + l * 6 + k];
  const float* ntnW = (const float*)d_in[19];
  const float* ntnV = (const float*)d_in[20];
  const float* ntnB = (const float*)d_in[21];
  const float* r0Wih = (const float*)d_in[22];
  const float* r0Whh = (const float*)d_in[23];
  const float* r0bih = (const float*)d_in[24];
  const float* r0bhh = (const float*)d_in[25];
  const float* r1Wih = (const float*)d_in[26];
  const float* r1Whh = (const float*)d_in[27];
  const float* r1bih = (const float*)d_in[28];
  const float* r1bhh = (const float*)d_in[29];
  const float* rlW = (const float*)d_in[30];
  const float* rlb = (const float*)d_in[31];
  const float* rkW1 = (const float*)d_in[32];
  const float* rkb1 = (const float*)d_in[33];
  const float* rkW2 = (const float*)d_in[34];
  const float* rkb2 = (const float*)d_in[35];
  const float* rkW3 = (const float*)d_in[36];
  const float* rkb3 = (const float*)d_in[37];
  const float* fc1W = (const float*)d_in[38];
  const float* fc1b = (const float*)d_in[39];
  const float* fc2W = (const float*)d_in[40];
  const float* fc2b = (const float*)d_in[41];
  const float* fc3W = (const float*)d_in[42];
  const float* fc3b = (const float*)d_in[43];

  // ---- workspace layout (~55 MB)
  char* base = (char*)d_ws;
  size_t woff = 0;
#define WS_ALLOC(T, NAME, BYTES) \
  T* NAME = (T*)(base + woff);   \
  woff = (woff + (size_t)(BYTES) + 255) & ~(size_t)255;
  WS_ALLOC(char, rnn_buf, (size_t)5242880)          // RNN/head overlay
  WS_ALLOC(u16, xb0, (size_t)N_NODES * XPAD * 2)
  WS_ALLOC(u16, xb1, (size_t)N_NODES * XPAD * 2)
  WS_ALLOC(u16, Pbuf0, (size_t)N_NODES * XPAD * 2)
  WS_ALLOC(u16, Qbuf0, (size_t)N_NODES * XPAD * 2)
  WS_ALLOC(u16, Pbuf1, (size_t)N_NODES * XPAD * 2)
  WS_ALLOC(u16, Qbuf1, (size_t)N_NODES * XPAD * 2)
  WS_ALLOC(u16, aggb0, (size_t)N_NODES * XPAD * 2)
  WS_ALLOC(u16, aggb1, (size_t)N_NODES * XPAD * 2)
  WS_ALLOC(u16, Wb0, (size_t)3 * 128 * 128 * 2)
  WS_ALLOC(u16, Wb1, (size_t)3 * 128 * 128 * 2)
  WS_ALLOC(u16, Wm, (size_t)4 * 128 * 128 * 2)      // [layer][W1,W2]
  WS_ALLOC(int, offAll, (size_t)2 * (N_NODES + 1) * 4)
  WS_ALLOC(int, cursor, (size_t)2 * N_NODES * 4)
  WS_ALLOC(int, bsum, (size_t)2 * SCAN_B * 4)
  WS_ALLOC(int, el0, (size_t)N_EDGES * 4)
  WS_ALLOC(int, el1, (size_t)N_EDGES * 4)
  WS_ALLOC(int, sp0, (size_t)N_EDGES * 4)
  WS_ALLOC(int, sp1, (size_t)N_EDGES * 4)
  WS_ALLOC(int, dp0, (size_t)N_EDGES * 4)
  WS_ALLOC(int, dp1, (size_t)N_EDGES * 4)
  WS_ALLOC(float, emb, (size_t)N_RULES * FEAT * 4)
  WS_ALLOC(float, scores, (size_t)N_RULES * 4)
  WS_ALLOC(int, topidx, (size_t)RULE_NUMS * 4)
  WS_ALLOC(float, gtp, (size_t)(2 * FEAT + NTN_OUT) * 4)
#undef WS_ALLOC
  u16* xb[2] = {xb0, xb1};
  u16* Wbl[2] = {Wb0, Wb1};
  float* gv = gtp;           // g1[100], g2[100]
  float* tp = gtp + 200;     // tp[200]

  // RNN / head scratch inside rnn_buf (serial stream, disjoint lifetimes)
  float* U   = (float*)rnn_buf;                          // [50][256][64] f32
  u16*   ys  = (u16*)(rnn_buf + 3276800);                // [3200][256] bf16
  float* hT  = (float*)(rnn_buf + 4915200);              // [64][256] f32
  float* featWS = (float*)(rnn_buf + 4980736);
  float* z1WS   = (float*)(rnn_buf + 4988160);

  hipMemsetAsync(cursor, 0, (size_t)2 * N_NODES * 4, stream);
  hipMemsetAsync(gtp, 0, (size_t)(2 * FEAT + NTN_OUT) * 4, stream);

  k_prep<<<2048, 256, 0, stream>>>(nf[0], nf[1], xb[0], xb[1]);
  k_wprep<<<192, 256, 0, stream>>>(cw[0][0], Wb0);
  k_wprep<<<192, 256, 0, stream>>>(cw[1][0], Wb1);
  k_wprep_sq<<<64, 256, 0, stream>>>(cw[0][2], Wm);                 // l0 W1
  k_wprep_sq<<<64, 256, 0, stream>>>(cw[0][4], Wm + 16384);         // l0 W2
  k_wprep_sq<<<64, 256, 0, stream>>>(cw[1][2], Wm + 2 * 16384);     // l1 W1
  k_wprep_sq<<<64, 256, 0, stream>>>(cw[1][4], Wm + 3 * 16384);     // l1 W2

  // ---- CSR both graphs
  const int* src0 = ei[0];
  const int* src1 = ei[1];
  const int* dst0 = ei[0] + N_EDGES;
  const int* dst1 = ei[1] + N_EDGES;
  k_count2<<<dim3(1250, 2), 256, 0, stream>>>(dst0, dst1, cursor);
  k_scan1<<<dim3(SCAN_B, 2), 256, 0, stream>>>(cursor, offAll, bsum);
  k_scan2<<<dim3(1, 2), 128, 0, stream>>>(bsum);
  k_scan3<<<dim3(SCAN_B, 2), 256, 0, stream>>>(bsum, offAll, cursor);
  k_scatter2<<<dim3(1250, 2), 256, 0, stream>>>(src0, dst0, src1, dst1, cursor,
                                                el0, el1, sp0, sp1, dp0, dp1);

  // ---- rule embedding (rnn_buf overlay; finishes before GNN phase)
  {
    dim3 gg(50, 2);
    k_gemm_u<0><<<gg, 256, 0, stream>>>(rules, nullptr, r0Wih, r0bih, r0bhh, U);
    k_rec<1><<<4, 512, 0, stream>>>(U, r0Whh, ys, nullptr);
    k_gemm_u<1><<<gg, 256, 0, stream>>>(nullptr, ys, r1Wih, r1bih, r1bhh, U);
    k_rec<0><<<4, 512, 0, stream>>>(U, r1Whh, nullptr, hT);
    k_rulelin<<<N_RULES, 128, 0, stream>>>(hT, rlW, rlb, emb);
  }
  k_ranker<<<N_RULES, 128, 0, stream>>>(emb, rkW1, rkb1, rkW2, rkb2, rkW3, rkb3,
                                        scores);
  k_topk<<<1, 64, 0, stream>>>(scores, topidx);

  // ---- GNN: 2 TripleConv layers, BOTH graphs per dispatch
  for (int l = 0; l < 2; ++l) {
    k_nodegemm<<<dim3(157, 2, 2), 256, 0, stream>>>(xb0, xb1, Wbl[l], cw[l][1],
                                                    Pbuf0, Qbuf0, Pbuf1, Qbuf1);
    k_msgagg2<<<dim3(N_NODES / NPB, 2), 256, 0, stream>>>(
        ef[0], ef[1], Wbl[l], el0, el1, sp0, sp1, dp0, dp1, offAll,
        Pbuf0, Qbuf0, Pbuf1, Qbuf1, xb0, xb1, aggb0, aggb1);
    k_mlp<<<dim3(157, 2), 256, 0, stream>>>(aggb0, aggb1,
                                            Wm + (size_t)(2 * l) * 16384, cw[l][3],
                                            Wm + (size_t)(2 * l + 1) * 16384,
                                            cw[l][5], xb0, xb1);
  }
  k_pool<<<200, 128, 0, stream>>>(xb0, gv);
  k_pool<<<200, 128, 0, stream>>>(xb1, gv + FEAT);

  // ---- NTN + head
  k_ntn<<<FEAT, 256, 0, stream>>>(ntnW, gv, gv + FEAT, tp);
  k_feat<<<1, 256, 0, stream>>>(tp, gv, ntnV, ntnB, emb, topidx, featWS);
  k_fc1<<<125, 256, 0, stream>>>(featWS, fc1W, fc1b, z1WS);
  k_head2<<<1, 128, 0, stream>>>(z1WS, fc2W, fc2b, fc3W, fc3b, (float*)d_out);
}

// Round 16
// 786.678 us; speedup vs baseline: 1.2252x; 1.2252x over previous
//
#include <hip/hip_runtime.h>

typedef unsigned short u16;
typedef unsigned int u32;

#define N_NODES 20000
#define N_EDGES 320000
#define FEAT 100
#define XPAD 112   // padded cols for bf16 node mirrors / P / Q / agg (14 x 16B rows)
#define N_RULES 64
#define T_RULE 50
#define H_RNN 256
#define RULE_NUMS 16
#define NTN_OUT 200
#define SCAN_B 79  // ceil(20000/256)
#define NPB 16     // nodes per k_msgagg2 block

typedef __attribute__((ext_vector_type(8))) short short8;
typedef __attribute__((ext_vector_type(4))) float f32x4;

__device__ __forceinline__ u16 f2bu(float f) {
  u32 u = __float_as_uint(f);
  u32 r = (u + 0x7fffu + ((u >> 16) & 1u)) >> 16;   // RNE
  return (u16)r;
}
__device__ __forceinline__ float bu2f(u16 u) {
  return __uint_as_float(((u32)u) << 16);
}
__device__ __forceinline__ u32 pk2(float a, float b) {
  return (u32)f2bu(a) | ((u32)f2bu(b) << 16);
}

__device__ __forceinline__ void lds_st16(void* base, int byteOff, uint4 v) {
  *(uint4*)((char*)base + byteOff) = v;
}
__device__ __forceinline__ short8 lds_ld16(const void* base, int byteOff) {
  return *(const short8*)((const char*)base + byteOff);
}

// XOR swizzle: rows of 256B (128 bf16), flip bits 4..6 by row&7 (G4 / T2)
#define SWZ(row, kByte) (((((row) << 8) + (kByte))) ^ (((row) & 7) << 4))

// H-state LDS swizzle (rows of 512B = 256 bf16): chunk' = (chunk + 5*row) & 31
__device__ __forceinline__ int hs_off(int row, int chunk) {
  return (row << 9) | (((chunk + row * 5) & 31) << 4);
}

__device__ __forceinline__ float tanh_fast(float x) {
  const float e = __expf(2.f * x);
  return 1.f - 2.f / (e + 1.f);
}

// ---------------------------------------------------------------- prep: bf16 mirrors
__global__ void k_prep(const float* __restrict__ nf0, const float* __restrict__ nf1,
                       u16* __restrict__ xb0, u16* __restrict__ xb1) {
  const int total = N_NODES * XPAD;
  for (int i = blockIdx.x * blockDim.x + threadIdx.x; i < total;
       i += gridDim.x * blockDim.x) {
    const int n = i / XPAD;
    const int c = i - n * XPAD;
    const float v0 = (c < FEAT) ? nf0[(size_t)n * FEAT + c] : 0.f;
    const float v1 = (c < FEAT) ? nf1[(size_t)n * FEAT + c] : 0.f;
    xb0[i] = f2bu(v0);
    xb1[i] = f2bu(v1);
  }
}

// ---------------------------------------------------------------- W -> bf16 [3][128][128]
__global__ void k_wprep(const float* __restrict__ linW, u16* __restrict__ Wb) {
  const int idx = blockIdx.x * blockDim.x + threadIdx.x;   // < 3*128*128
  if (idx >= 3 * 128 * 128) return;
  const int c = idx >> 14;
  const int rem = idx & 16383;
  const int r = rem >> 7;
  const int k = rem & 127;
  u16 v = 0;
  if (r < FEAT && k < FEAT) v = f2bu(linW[(size_t)r * 300 + c * 100 + k]);
  Wb[idx] = v;
}

// square [100][100] fp32 -> [128][128] bf16 zero-padded
__global__ void k_wprep_sq(const float* __restrict__ W, u16* __restrict__ Wb) {
  const int idx = blockIdx.x * blockDim.x + threadIdx.x;   // < 128*128
  if (idx >= 128 * 128) return;
  const int r = idx >> 7;
  const int k = idx & 127;
  u16 v = 0;
  if (r < FEAT && k < FEAT) v = f2bu(W[(size_t)r * FEAT + k]);
  Wb[idx] = v;
}

// ---------------------------------------------------------------- CSR build (both graphs)
__global__ void k_count2(const int* __restrict__ d0, const int* __restrict__ d1,
                         int* __restrict__ cnt) {
  const int e = blockIdx.x * blockDim.x + threadIdx.x;
  const int* d = blockIdx.y ? d1 : d0;
  if (e < N_EDGES) atomicAdd(&cnt[blockIdx.y * N_NODES + d[e]], 1);
}

__global__ __launch_bounds__(256) void k_scan1(const int* __restrict__ cnt,
                                               int* __restrict__ off,
                                               int* __restrict__ bsum) {
  __shared__ int buf[256];
  const int g = blockIdx.y, b = blockIdx.x, tid = threadIdx.x;
  const int i = b * 256 + tid;
  const int v = (i < N_NODES) ? cnt[g * N_NODES + i] : 0;
  buf[tid] = v;
  __syncthreads();
  for (int ofs = 1; ofs < 256; ofs <<= 1) {
    const int t = (tid >= ofs) ? buf[tid - ofs] : 0;
    __syncthreads();
    buf[tid] += t;
    __syncthreads();
  }
  if (i < N_NODES) off[g * (N_NODES + 1) + i] = buf[tid] - v;  // excl within block
  if (tid == 255) bsum[g * SCAN_B + b] = buf[255];
}

__global__ __launch_bounds__(128) void k_scan2(int* __restrict__ bsum) {
  __shared__ int s[128];
  const int g = blockIdx.y, tid = threadIdx.x;
  const int v = (tid < SCAN_B) ? bsum[g * SCAN_B + tid] : 0;
  s[tid] = v;
  __syncthreads();
  for (int ofs = 1; ofs < 128; ofs <<= 1) {
    const int t = (tid >= ofs) ? s[tid - ofs] : 0;
    __syncthreads();
    s[tid] += t;
    __syncthreads();
  }
  if (tid < SCAN_B) bsum[g * SCAN_B + tid] = s[tid] - v;  // exclusive
}

__global__ __launch_bounds__(256) void k_scan3(const int* __restrict__ bsum,
                                               int* __restrict__ off,
                                               int* __restrict__ cursor) {
  const int g = blockIdx.y, b = blockIdx.x, tid = threadIdx.x;
  const int i = b * 256 + tid;
  if (i < N_NODES) {
    const int o = off[g * (N_NODES + 1) + i] + bsum[g * SCAN_B + b];
    off[g * (N_NODES + 1) + i] = o;
    cursor[g * N_NODES + i] = o;
  }
  if (i == N_NODES) off[g * (N_NODES + 1) + N_NODES] = N_EDGES;
}

// per CSR slot: elist[pos]=edge id, spos[pos]=src node, dpos[pos]=dst node
__global__ void k_scatter2(const int* __restrict__ s0, const int* __restrict__ d0,
                           const int* __restrict__ s1, const int* __restrict__ d1,
                           int* __restrict__ cursor,
                           int* __restrict__ el0, int* __restrict__ el1,
                           int* __restrict__ sp0, int* __restrict__ sp1,
                           int* __restrict__ dp0, int* __restrict__ dp1) {
  const int e = blockIdx.x * blockDim.x + threadIdx.x;
  const int g = blockIdx.y;
  const int* d = g ? d1 : d0;
  const int* s = g ? s1 : s0;
  if (e < N_EDGES) {
    const int dn = d[e];
    const int pos = atomicAdd(&cursor[g * N_NODES + dn], 1);
    (g ? el1 : el0)[pos] = e;
    (g ? sp1 : sp0)[pos] = s[e];
    (g ? dp1 : dp0)[pos] = dn;
  }
}

// ---------------------------------------------------------------- RNN input-GEMM
// U layout (transposed for k_rec): U[(t*256 + col)*64 + r],  global row gm = t*64+r
template <int VARIANT>
__global__ __launch_bounds__(256) void k_gemm_u(
    const float* __restrict__ Af, const u16* __restrict__ Ab,
    const float* __restrict__ W, const float* __restrict__ b0,
    const float* __restrict__ b1, float* __restrict__ Uout) {
  __shared__ __align__(16) u16 As[64 * 128];   // 16 KB
  __shared__ __align__(16) u16 Bs[128 * 128];  // 32 KB
  const int tid = threadIdx.x;
  const int lane = tid & 63;
  const int wv = tid >> 6;
  const int l15 = lane & 15;
  const int lhi = lane >> 4;
  const int mb = blockIdx.x * 64;
  const int nb = blockIdx.y * 128;
  const int rb = (wv >> 1) * 32;
  const int cb = (wv & 1) * 64;
  constexpr int KV = VARIANT ? 256 : 100;       // valid K
  constexpr int NPH = VARIANT ? 2 : 1;          // 128-wide K phases

  f32x4 acc[2][4];
  const f32x4 z4 = {0.f, 0.f, 0.f, 0.f};
#pragma unroll
  for (int i = 0; i < 2; ++i)
#pragma unroll
    for (int j = 0; j < 4; ++j) acc[i][j] = z4;

  for (int kc = 0; kc < NPH; ++kc) {
    __syncthreads();
    // ---- stage A (64 rows x 128 local-k)
    {
      const int row = tid >> 2;
      const int k0 = (tid & 3) * 32;
      const int gm = mb + row;
      if (VARIANT == 0) {
        const int r = gm & 63;
        const int t = gm >> 6;
        const float* ar = Af + ((size_t)r * T_RULE + t) * FEAT;
#pragma unroll
        for (int c = 0; c < 4; ++c) {
          const int k = k0 + c * 8;
          uint4 v = {0u, 0u, 0u, 0u};
          if (k + 8 <= KV) {
            const float4 fa = *(const float4*)(ar + k);
            const float4 fb = *(const float4*)(ar + k + 4);
            v.x = pk2(fa.x, fa.y); v.y = pk2(fa.z, fa.w);
            v.z = pk2(fb.x, fb.y); v.w = pk2(fb.z, fb.w);
          } else if (k < KV) {   // k == 96
            const float4 fa = *(const float4*)(ar + k);
            v.x = pk2(fa.x, fa.y); v.y = pk2(fa.z, fa.w);
          }
          lds_st16(As, SWZ(row, k * 2), v);
        }
      } else {
        const uint4* ar = (const uint4*)(Ab + (size_t)gm * 256 + kc * 128 + k0);
#pragma unroll
        for (int c = 0; c < 4; ++c)
          lds_st16(As, SWZ(row, (k0 + c * 8) * 2), ar[c]);
      }
    }
    // ---- stage B (128 N-rows x 128 local-k)
    {
      const int row = tid >> 1;
      const int k0 = (tid & 1) * 64;
      const float* wr = W + (size_t)(nb + row) * KV;
#pragma unroll
      for (int c = 0; c < 8; ++c) {
        const int k = k0 + c * 8;
        const int kg = kc * 128 + k;
        uint4 v = {0u, 0u, 0u, 0u};
        if (kg + 8 <= KV) {
          const float4 fa = *(const float4*)(wr + kg);
          const float4 fb = *(const float4*)(wr + kg + 4);
          v.x = pk2(fa.x, fa.y); v.y = pk2(fa.z, fa.w);
          v.z = pk2(fb.x, fb.y); v.w = pk2(fb.z, fb.w);
        } else if (kg < KV) {
          const float4 fa = *(const float4*)(wr + kg);
          v.x = pk2(fa.x, fa.y); v.y = pk2(fa.z, fa.w);
        }
        lds_st16(Bs, SWZ(row, k * 2), v);
      }
    }
    __syncthreads();
#pragma unroll
    for (int s = 0; s < 4; ++s) {
      const int kByte = s * 64 + lhi * 16;
      short8 af[2], bfr[4];
#pragma unroll
      for (int i = 0; i < 2; ++i)
        af[i] = lds_ld16(As, SWZ(rb + i * 16 + l15, kByte));
#pragma unroll
      for (int j = 0; j < 4; ++j)
        bfr[j] = lds_ld16(Bs, SWZ(cb + j * 16 + l15, kByte));
#pragma unroll
      for (int i = 0; i < 2; ++i)
#pragma unroll
        for (int j = 0; j < 4; ++j)
          acc[i][j] = __builtin_amdgcn_mfma_f32_16x16x32_bf16(af[i], bfr[j],
                                                              acc[i][j], 0, 0, 0);
    }
  }
  // ---- epilogue: + (bih + bhh), transposed float4 store
#pragma unroll
  for (int j = 0; j < 4; ++j) {
    const int col = nb + cb + j * 16 + l15;
    const float bias = b0[col] + b1[col];
#pragma unroll
    for (int i = 0; i < 2; ++i) {
      const int base_m = mb + rb + i * 16 + lhi * 4;
      const int t = base_m >> 6;
      const int r0 = base_m & 63;
      float4 st;
      st.x = acc[i][j][0] + bias; st.y = acc[i][j][1] + bias;
      st.z = acc[i][j][2] + bias; st.w = acc[i][j][3] + bias;
      *(float4*)(Uout + ((size_t)t * 256 + col) * 64 + r0) = st;
    }
  }
}

// ---------------------------------------------------------------- RNN recurrence
template <int WRITE_YS>
__global__ __launch_bounds__(512) void k_rec(
    const float* __restrict__ U, const float* __restrict__ Whh,
    u16* __restrict__ ys, float* __restrict__ hT) {
  __shared__ __align__(16) u16 Hs[16 * 256];   // 8 KB
  const int tid = threadIdx.x;
  const int lane = tid & 63;
  const int wv = tid >> 6;          // 8 waves -> 32 cols each
  const int cbase = wv * 32;
  const int ruleBase = blockIdx.x * 16;
  const int l15 = lane & 15;
  const int lhi = lane >> 4;

  short8 bf[2][8];
#pragma unroll
  for (int jt = 0; jt < 2; ++jt) {
    const int col = cbase + jt * 16 + l15;
    const float* wr = Whh + (size_t)col * 256;
#pragma unroll
    for (int s = 0; s < 8; ++s) {
      const int k0 = s * 32 + lhi * 8;
      const float4 fa = *(const float4*)(wr + k0);
      const float4 fb = *(const float4*)(wr + k0 + 4);
      uint4 v;
      v.x = pk2(fa.x, fa.y); v.y = pk2(fa.z, fa.w);
      v.z = pk2(fb.x, fb.y); v.w = pk2(fb.z, fb.w);
      bf[jt][s] = *(short8*)&v;
    }
  }
  for (int i = tid; i < 16 * 256 / 8; i += 512) {
    const uint4 z = {0u, 0u, 0u, 0u};
    ((uint4*)Hs)[i] = z;
  }
  __syncthreads();

  const int n0 = cbase + l15;
  const int n1 = cbase + 16 + l15;
  const int m0 = lhi * 4;
  float4 Ua0 = *(const float4*)(U + ((size_t)n0) * 64 + m0);
  float4 Ua1 = *(const float4*)(U + ((size_t)n1) * 64 + m0);

  const f32x4 z4 = {0.f, 0.f, 0.f, 0.f};
  float hv[2][4];
  for (int t = 0; t < T_RULE; ++t) {
    const int tn = (t + 1 < T_RULE) ? t + 1 : t;
    const float4 Ub0 = *(const float4*)(U + ((size_t)tn * 256 + n0) * 64 + m0);
    const float4 Ub1 = *(const float4*)(U + ((size_t)tn * 256 + n1) * 64 + m0);
    f32x4 acc[2] = {z4, z4};
#pragma unroll
    for (int s = 0; s < 8; ++s) {
      const short8 af = lds_ld16(Hs, hs_off(l15, s * 4 + lhi));
      acc[0] = __builtin_amdgcn_mfma_f32_16x16x32_bf16(af, bf[0][s], acc[0], 0, 0, 0);
      acc[1] = __builtin_amdgcn_mfma_f32_16x16x32_bf16(af, bf[1][s], acc[1], 0, 0, 0);
    }
    const float ua0[4] = {Ua0.x, Ua0.y, Ua0.z, Ua0.w};
    const float ua1[4] = {Ua1.x, Ua1.y, Ua1.z, Ua1.w};
#pragma unroll
    for (int q = 0; q < 4; ++q) {
      hv[0][q] = tanh_fast(ua0[q] + acc[0][q]);
      hv[1][q] = tanh_fast(ua1[q] + acc[1][q]);
    }
    __syncthreads();   // all Hs reads done before overwrite
#pragma unroll
    for (int jt = 0; jt < 2; ++jt) {
      const int n = cbase + jt * 16 + l15;
#pragma unroll
      for (int q = 0; q < 4; ++q) {
        const int m = lhi * 4 + q;
        const u16 hb = f2bu(hv[jt][q]);
        *(u16*)((char*)Hs + (hs_off(m, n >> 3) + ((n & 7) << 1))) = hb;
        if (WRITE_YS)
          ys[(((size_t)t * 64 + ruleBase + m) << 8) + n] = hb;
      }
    }
    Ua0 = Ub0; Ua1 = Ub1;
    __syncthreads();
  }
  if (!WRITE_YS) {
#pragma unroll
    for (int jt = 0; jt < 2; ++jt) {
      const int n = cbase + jt * 16 + l15;
#pragma unroll
      for (int q = 0; q < 4; ++q) {
        const int m = lhi * 4 + q;
        hT[((size_t)(ruleBase + m) << 8) + n] = hv[jt][q];
      }
    }
  }
}

// ---------------------------------------------------------------- rule linear
__global__ __launch_bounds__(128) void k_rulelin(
    const float* __restrict__ hT, const float* __restrict__ rlW,
    const float* __restrict__ rlb, float* __restrict__ emb) {
  __shared__ __align__(16) float hs[H_RNN];
  const int b = blockIdx.x;
  const int tid = threadIdx.x;
  for (int i = tid; i < H_RNN / 4; i += 128)
    ((float4*)hs)[i] = ((const float4*)(hT + (size_t)b * H_RNN))[i];
  __syncthreads();
  if (tid < FEAT) {
    float acc = rlb[tid];
    const float4* w = (const float4*)(rlW + (size_t)tid * H_RNN);
    const float4* hv = (const float4*)hs;
#pragma unroll 8
    for (int k = 0; k < 64; ++k) {
      const float4 a = w[k], x = hv[k];
      acc += a.x * x.x + a.y * x.y + a.z * x.z + a.w * x.w;
    }
    emb[(size_t)b * FEAT + tid] = acc;
  }
}

// ---------------------------------------------------------------- rule ranker
__global__ __launch_bounds__(128) void k_ranker(
    const float* __restrict__ emb,
    const float* __restrict__ W1, const float* __restrict__ b1,
    const float* __restrict__ W2, const float* __restrict__ b2,
    const float* __restrict__ W3, const float* __restrict__ b3,
    float* __restrict__ scores) {
  __shared__ float eb[FEAT];
  __shared__ float h1s[128];
  __shared__ float h2s[64];
  const int r = blockIdx.x;
  const int tid = threadIdx.x;
  if (tid < FEAT) eb[tid] = emb[(size_t)r * FEAT + tid];
  __syncthreads();
  {
    float acc = b1[tid];
    const float* w = W1 + (size_t)tid * FEAT;
    for (int k = 0; k < FEAT; ++k) acc += w[k] * eb[k];
    h1s[tid] = acc > 0.f ? acc : 0.f;
  }
  __syncthreads();
  if (tid < 64) {
    float acc = b2[tid];
    const float* w = W2 + (size_t)tid * 128;
    for (int k = 0; k < 128; ++k) acc += w[k] * h1s[k];
    h2s[tid] = acc > 0.f ? acc : 0.f;
  }
  __syncthreads();
  if (tid == 0) {
    float acc = b3[0];
    for (int k = 0; k < 64; ++k) acc += W3[k] * h2s[k];
    scores[r] = acc;   // sigmoid omitted: monotonic, ranking preserved
  }
}

__global__ void k_topk(const float* __restrict__ scores, int* __restrict__ topidx) {
  if (threadIdx.x == 0 && blockIdx.x == 0) {
    float s[N_RULES];
    for (int i = 0; i < N_RULES; ++i) s[i] = scores[i];
    for (int t = 0; t < RULE_NUMS; ++t) {
      int best = 0;
      float bv = s[0];
      for (int i = 1; i < N_RULES; ++i)
        if (s[i] > bv) { bv = s[i]; best = i; }
      topidx[t] = best;
      s[best] = -1e30f;
    }
  }
}

// ---------------------------------------------------------------- P/Q node GEMM (both graphs)
// grid: (157, 2 = P|Q, 2 = graph)
__global__ __launch_bounds__(256) void k_nodegemm(
    const u16* __restrict__ xbA, const u16* __restrict__ xbB,
    const u16* __restrict__ Wb, const float* __restrict__ linB,
    u16* __restrict__ PA, u16* __restrict__ QA,
    u16* __restrict__ PB, u16* __restrict__ QB) {
  __shared__ __align__(16) u16 As[128 * 128];
  __shared__ __align__(16) u16 Bs[128 * 128];
  const int tid = threadIdx.x;
  const int lane = tid & 63;
  const int wv = tid >> 6;
  const int l15 = lane & 15;
  const int lhi = lane >> 4;
  const int n0 = blockIdx.x * 128;
  const int p = blockIdx.y;
  const int gph = blockIdx.z;
  const u16* xb = gph ? xbB : xbA;
  u16* Out = gph ? (p ? QB : PB) : (p ? QA : PA);
  const int rStage = tid >> 1;
  const int hf = tid & 1;
  const int rb = (wv >> 1) * 64;
  const int cb = (wv & 1) * 64;

  {
    const int node = n0 + rStage;
    const bool ok = node < N_NODES;
    const uint4* xr = (const uint4*)(xb + (size_t)node * XPAD);
#pragma unroll
    for (int q = 0; q < 8; ++q) {
      const int cc = hf * 8 + q;
      uint4 v = {0u, 0u, 0u, 0u};
      if (ok && cc < 14) v = xr[cc];
      lds_st16(As, SWZ(rStage, cc * 16), v);
    }
  }
  {
    const uint4* wr = (const uint4*)(Wb + (size_t)(p ? 2 : 0) * 16384 +
                                     (size_t)rStage * 128);
#pragma unroll
    for (int q = 0; q < 8; ++q) {
      const int cc = hf * 8 + q;
      lds_st16(Bs, SWZ(rStage, cc * 16), wr[cc]);
    }
  }
  __syncthreads();

  f32x4 acc[4][4];
  const f32x4 z4 = {0.f, 0.f, 0.f, 0.f};
#pragma unroll
  for (int i = 0; i < 4; ++i)
#pragma unroll
    for (int j = 0; j < 4; ++j) acc[i][j] = z4;
#pragma unroll
  for (int s = 0; s < 4; ++s) {
    const int kByte = s * 64 + lhi * 16;
    short8 af[4], bfr[4];
#pragma unroll
    for (int i = 0; i < 4; ++i) {
      af[i] = lds_ld16(As, SWZ(rb + i * 16 + l15, kByte));
      bfr[i] = lds_ld16(Bs, SWZ(cb + i * 16 + l15, kByte));
    }
#pragma unroll
    for (int i = 0; i < 4; ++i)
#pragma unroll
      for (int j = 0; j < 4; ++j)
        acc[i][j] = __builtin_amdgcn_mfma_f32_16x16x32_bf16(af[i], bfr[j],
                                                            acc[i][j], 0, 0, 0);
  }
#pragma unroll
  for (int j = 0; j < 4; ++j) {
    const int col = cb + j * 16 + l15;
    if (col >= XPAD) continue;
    const bool valid = col < FEAT;
    const float bias = (valid && !p) ? linB[col] : 0.f;
#pragma unroll
    for (int i = 0; i < 4; ++i) {
      const int row0 = rb + i * 16 + lhi * 4;
#pragma unroll
      for (int q = 0; q < 4; ++q) {
        const int node = n0 + row0 + q;
        if (node < N_NODES)
          Out[(size_t)node * XPAD + col] = valid ? f2bu(acc[i][j][q] + bias) : (u16)0;
      }
    }
  }
}

// ---------------------------------------------------------------- fused message+aggregate v2 (both graphs)
// grid: (1250, 2 = graph). Block owns NPB=16 whole nodes of its graph.
__global__ __launch_bounds__(256, 3) void k_msgagg2(
    const float* __restrict__ efA, const float* __restrict__ efB,
    const u16* __restrict__ Wb,
    const int* __restrict__ elA, const int* __restrict__ elB,
    const int* __restrict__ spA, const int* __restrict__ spB,
    const int* __restrict__ dpA, const int* __restrict__ dpB,
    const int* __restrict__ offAll,
    const u16* __restrict__ PA, const u16* __restrict__ QA,
    const u16* __restrict__ PB, const u16* __restrict__ QB,
    const u16* __restrict__ xbA, const u16* __restrict__ xbB,
    u16* __restrict__ aggA, u16* __restrict__ aggB) {
  __shared__ __align__(16) u16 As[64 * 128];   // 16 KB
  const int gph = blockIdx.y;
  const float* ef = gph ? efB : efA;
  const int* elist = gph ? elB : elA;
  const int* spos = gph ? spB : spA;
  const int* dpos = gph ? dpB : dpA;
  const int* off = offAll + gph * (N_NODES + 1);
  const u16* Pb = gph ? PB : PA;
  const u16* Qb = gph ? QB : QA;
  const u16* xb = gph ? xbB : xbA;
  u16* aggb = gph ? aggB : aggA;

  const int tid = threadIdx.x;
  const int lane = tid & 63;
  const int wv = tid >> 6;
  const int l15 = lane & 15;
  const int lhi = lane >> 4;
  const int nb0 = blockIdx.x * NPB;
  const int rr = tid >> 2;          // tile row 0..63
  const int t4 = tid & 3;
  const int cb = wv * 32;           // wave: all 64 rows x cols cb..cb+31
  const f32x4 z4 = {0.f, 0.f, 0.f, 0.f};

  const int p0 = off[nb0];
  const int pEnd = off[nb0 + NPB];

  // segsum mapping: thread = (local node sl, 8-col chunk sc8); 16x16 = 256
  const int sl = tid >> 4;
  const int sc8 = tid & 15;
  const int myS = off[nb0 + sl];
  const int myE = off[nb0 + sl + 1];
  float a8[8] = {0.f, 0.f, 0.f, 0.f, 0.f, 0.f, 0.f, 0.f};

  // ---- We B-fragments -> registers (2 col-tiles x 4 k-steps = 32 VGPR)
  short8 bf[2][4];
  {
    const u16* wbase = Wb + 16384;  // chunk 1 = We
#pragma unroll
    for (int jt = 0; jt < 2; ++jt) {
      const u16* wr = wbase + (size_t)(cb + jt * 16 + l15) * 128;
#pragma unroll
      for (int s = 0; s < 4; ++s)
        bf[jt][s] = *(const short8*)(wr + s * 32 + lhi * 8);
    }
  }

  for (int base = p0; base < pEnd; base += 64) {
    const int slot = base + rr;
    const bool valid = slot < pEnd;
    // ---- stage A: gather ef rows (400B each, float4-aligned)
    {
      const int e = valid ? elist[slot] : 0;
      const int k0 = t4 * 32;
      const float* ar = ef + (size_t)e * FEAT;
#pragma unroll
      for (int c = 0; c < 4; ++c) {
        const int k = k0 + c * 8;
        uint4 v = {0u, 0u, 0u, 0u};
        if (valid) {
          if (k + 8 <= FEAT) {
            const float4 fa = *(const float4*)(ar + k);
            const float4 fb = *(const float4*)(ar + k + 4);
            v.x = pk2(fa.x, fa.y); v.y = pk2(fa.z, fa.w);
            v.z = pk2(fb.x, fb.y); v.w = pk2(fb.z, fb.w);
          } else if (k < FEAT) {   // k == 96
            const float4 fa = *(const float4*)(ar + k);
            v.x = pk2(fa.x, fa.y); v.y = pk2(fa.z, fa.w);
          }
        }
        lds_st16(As, SWZ(rr, k * 2), v);
      }
    }
    __syncthreads();
    // ---- MFMA: 64x128 tile; wave covers 4 row-tiles x 2 col-tiles
    f32x4 acc[4][2];
#pragma unroll
    for (int i = 0; i < 4; ++i)
#pragma unroll
      for (int j = 0; j < 2; ++j) acc[i][j] = z4;
#pragma unroll
    for (int s = 0; s < 4; ++s) {
      const int kByte = s * 64 + lhi * 16;
      short8 af[4];
#pragma unroll
      for (int i = 0; i < 4; ++i)
        af[i] = lds_ld16(As, SWZ(i * 16 + l15, kByte));
#pragma unroll
      for (int i = 0; i < 4; ++i)
#pragma unroll
        for (int j = 0; j < 2; ++j)
          acc[i][j] = __builtin_amdgcn_mfma_f32_16x16x32_bf16(af[i], bf[j][s],
                                                              acc[i][j], 0, 0, 0);
    }
    __syncthreads();
    // ---- E tile -> LDS (bf16, swizzled; reuse As)
#pragma unroll
    for (int i = 0; i < 4; ++i) {
#pragma unroll
      for (int j = 0; j < 2; ++j) {
        const int col = cb + j * 16 + l15;
#pragma unroll
        for (int q = 0; q < 4; ++q) {
          const int row = i * 16 + lhi * 4 + q;
          *(u16*)((char*)As + (SWZ(row, col * 2))) = f2bu(acc[i][j][q]);
        }
      }
    }
    __syncthreads();
    // ---- row pass: m = relu(E + P[dst] + Q[src]) back into LDS (chunks 0..13)
    {
      const int dn = valid ? dpos[slot] : 0;
      const int sn = valid ? spos[slot] : 0;
#pragma unroll
      for (int c = 0; c < 4; ++c) {
        const int chunk = t4 * 4 + c;
        if (chunk >= 14) break;   // cols 112..127 stay as E (= 0)
        const uint4 p4 = *(const uint4*)(Pb + (size_t)dn * XPAD + chunk * 8);
        const uint4 q4 = *(const uint4*)(Qb + (size_t)sn * XPAD + chunk * 8);
        const short8 ev = lds_ld16(As, SWZ(rr, chunk * 16));
        const uint4 e4 = *(const uint4*)&ev;
        uint4 o;
        float v0 = bu2f((u16)(e4.x & 0xffffu)) + bu2f((u16)(p4.x & 0xffffu)) +
                   bu2f((u16)(q4.x & 0xffffu));
        float v1 = bu2f((u16)(e4.x >> 16)) + bu2f((u16)(p4.x >> 16)) +
                   bu2f((u16)(q4.x >> 16));
        o.x = pk2(v0 > 0.f ? v0 : 0.f, v1 > 0.f ? v1 : 0.f);
        float v2 = bu2f((u16)(e4.y & 0xffffu)) + bu2f((u16)(p4.y & 0xffffu)) +
                   bu2f((u16)(q4.y & 0xffffu));
        float v3 = bu2f((u16)(e4.y >> 16)) + bu2f((u16)(p4.y >> 16)) +
                   bu2f((u16)(q4.y >> 16));
        o.y = pk2(v2 > 0.f ? v2 : 0.f, v3 > 0.f ? v3 : 0.f);
        float v4 = bu2f((u16)(e4.z & 0xffffu)) + bu2f((u16)(p4.z & 0xffffu)) +
                   bu2f((u16)(q4.z & 0xffffu));
        float v5 = bu2f((u16)(e4.z >> 16)) + bu2f((u16)(p4.z >> 16)) +
                   bu2f((u16)(q4.z >> 16));
        o.z = pk2(v4 > 0.f ? v4 : 0.f, v5 > 0.f ? v5 : 0.f);
        float v6 = bu2f((u16)(e4.w & 0xffffu)) + bu2f((u16)(p4.w & 0xffffu)) +
                   bu2f((u16)(q4.w & 0xffffu));
        float v7 = bu2f((u16)(e4.w >> 16)) + bu2f((u16)(p4.w >> 16)) +
                   bu2f((u16)(q4.w >> 16));
        o.w = pk2(v6 > 0.f ? v6 : 0.f, v7 > 0.f ? v7 : 0.f);
        lds_st16(As, SWZ(rr, chunk * 16), o);
      }
    }
    __syncthreads();
    // ---- register segment-sum: thread (sl, sc8) owns node nb0+sl cols sc8*8..+7
    {
      const int gs = myS > base ? myS : base;
      const int ge = myE < base + 64 ? myE : base + 64;
      for (int r = gs; r < ge; ++r) {
        const short8 mv = lds_ld16(As, SWZ(r - base, sc8 * 16));
        const uint4 m4 = *(const uint4*)&mv;
        a8[0] += bu2f((u16)(m4.x & 0xffffu)); a8[1] += bu2f((u16)(m4.x >> 16));
        a8[2] += bu2f((u16)(m4.y & 0xffffu)); a8[3] += bu2f((u16)(m4.y >> 16));
        a8[4] += bu2f((u16)(m4.z & 0xffffu)); a8[5] += bu2f((u16)(m4.z >> 16));
        a8[6] += bu2f((u16)(m4.w & 0xffffu)); a8[7] += bu2f((u16)(m4.w >> 16));
      }
    }
    __syncthreads();   // before next tile overwrites As
  }
  // ---- epilogue: + xb residual, write aggb (bf16); chunks 0..13 cover XPAD
  if (sc8 < 14) {
    const int node = nb0 + sl;
    const uint4 xv = *(const uint4*)(xb + (size_t)node * XPAD + sc8 * 8);
    uint4 o;
    o.x = pk2(a8[0] + bu2f((u16)(xv.x & 0xffffu)),
              a8[1] + bu2f((u16)(xv.x >> 16)));
    o.y = pk2(a8[2] + bu2f((u16)(xv.y & 0xffffu)),
              a8[3] + bu2f((u16)(xv.y >> 16)));
    o.z = pk2(a8[4] + bu2f((u16)(xv.z & 0xffffu)),
              a8[5] + bu2f((u16)(xv.z >> 16)));
    o.w = pk2(a8[6] + bu2f((u16)(xv.w & 0xffffu)),
              a8[7] + bu2f((u16)(xv.w >> 16)));
    *(uint4*)(aggb + (size_t)node * XPAD + sc8 * 8) = o;
  }
}

// ---------------------------------------------------------------- node MLP (both graphs)
// grid: (157, 2 = graph)
__global__ __launch_bounds__(256) void k_mlp(
    const u16* __restrict__ aggA, const u16* __restrict__ aggB,
    const u16* __restrict__ W1b, const float* __restrict__ b1,
    const u16* __restrict__ W2b, const float* __restrict__ b2,
    u16* __restrict__ xbA, u16* __restrict__ xbB) {
  __shared__ __align__(16) u16 As[128 * 128];
  __shared__ __align__(16) u16 Bs[128 * 128];
  const int gph = blockIdx.y;
  const u16* aggb = gph ? aggB : aggA;
  u16* xbout = gph ? xbB : xbA;
  const int tid = threadIdx.x;
  const int lane = tid & 63;
  const int wv = tid >> 6;
  const int l15 = lane & 15;
  const int lhi = lane >> 4;
  const int n0 = blockIdx.x * 128;
  const int rStage = tid >> 1;
  const int hf = tid & 1;
  const int rb = (wv >> 1) * 64;
  const int cb = (wv & 1) * 64;
  const f32x4 z4 = {0.f, 0.f, 0.f, 0.f};

  // ---- stage A: agg rows (pre-padded bf16, straight copies)
  {
    const int node = n0 + rStage;
    const bool ok = node < N_NODES;
    const uint4* xr = (const uint4*)(aggb + (size_t)node * XPAD);
#pragma unroll
    for (int q = 0; q < 8; ++q) {
      const int cc = hf * 8 + q;
      uint4 v = {0u, 0u, 0u, 0u};
      if (ok && cc < 14) v = xr[cc];
      lds_st16(As, SWZ(rStage, cc * 16), v);
    }
  }
  // ---- stage B: W1b
  {
    const uint4* wr = (const uint4*)(W1b + (size_t)rStage * 128);
#pragma unroll
    for (int q = 0; q < 8; ++q) {
      const int cc = hf * 8 + q;
      lds_st16(Bs, SWZ(rStage, cc * 16), wr[cc]);
    }
  }
  __syncthreads();

  f32x4 acc[4][4];
#pragma unroll
  for (int i = 0; i < 4; ++i)
#pragma unroll
    for (int j = 0; j < 4; ++j) acc[i][j] = z4;
#pragma unroll
  for (int s = 0; s < 4; ++s) {
    const int kByte = s * 64 + lhi * 16;
    short8 af[4], bfr[4];
#pragma unroll
    for (int i = 0; i < 4; ++i) {
      af[i] = lds_ld16(As, SWZ(rb + i * 16 + l15, kByte));
      bfr[i] = lds_ld16(Bs, SWZ(cb + i * 16 + l15, kByte));
    }
#pragma unroll
    for (int i = 0; i < 4; ++i)
#pragma unroll
      for (int j = 0; j < 4; ++j)
        acc[i][j] = __builtin_amdgcn_mfma_f32_16x16x32_bf16(af[i], bfr[j],
                                                            acc[i][j], 0, 0, 0);
  }
  __syncthreads();
  // ---- epilogue 1: h = relu(acc + b1) -> As (cols >=100 are 0 automatically)
#pragma unroll
  for (int j = 0; j < 4; ++j) {
    const int col = cb + j * 16 + l15;
    const float bias = (col < FEAT) ? b1[col] : 0.f;
#pragma unroll
    for (int i = 0; i < 4; ++i) {
      const int row0 = rb + i * 16 + lhi * 4;
#pragma unroll
      for (int q = 0; q < 4; ++q) {
        float v = acc[i][j][q] + bias;
        v = v > 0.f ? v : 0.f;
        *(u16*)((char*)As + (SWZ(row0 + q, col * 2))) = f2bu(v);
      }
    }
  }
  // ---- stage B2: W2b
  {
    const uint4* wr = (const uint4*)(W2b + (size_t)rStage * 128);
#pragma unroll
    for (int q = 0; q < 8; ++q) {
      const int cc = hf * 8 + q;
      lds_st16(Bs, SWZ(rStage, cc * 16), wr[cc]);
    }
  }
  __syncthreads();

#pragma unroll
  for (int i = 0; i < 4; ++i)
#pragma unroll
    for (int j = 0; j < 4; ++j) acc[i][j] = z4;
#pragma unroll
  for (int s = 0; s < 4; ++s) {
    const int kByte = s * 64 + lhi * 16;
    short8 af[4], bfr[4];
#pragma unroll
    for (int i = 0; i < 4; ++i) {
      af[i] = lds_ld16(As, SWZ(rb + i * 16 + l15, kByte));
      bfr[i] = lds_ld16(Bs, SWZ(cb + i * 16 + l15, kByte));
    }
#pragma unroll
    for (int i = 0; i < 4; ++i)
#pragma unroll
      for (int j = 0; j < 4; ++j)
        acc[i][j] = __builtin_amdgcn_mfma_f32_16x16x32_bf16(af[i], bfr[j],
                                                            acc[i][j], 0, 0, 0);
  }
  // ---- epilogue 2: out = relu(acc + b2) -> xb (bf16, pads zeroed)
#pragma unroll
  for (int j = 0; j < 4; ++j) {
    const int col = cb + j * 16 + l15;
    if (col >= XPAD) continue;
    const bool valid = col < FEAT;
    const float bias = valid ? b2[col] : 0.f;
#pragma unroll
    for (int i = 0; i < 4; ++i) {
      const int row0 = rb + i * 16 + lhi * 4;
#pragma unroll
      for (int q = 0; q < 4; ++q) {
        const int node = n0 + row0 + q;
        if (node < N_NODES) {
          float v = acc[i][j][q] + bias;
          v = v > 0.f ? v : 0.f;
          xbout[(size_t)node * XPAD + col] = valid ? f2bu(v) : (u16)0;
        }
      }
    }
  }
}

// ---------------------------------------------------------------- global add pool (bf16 in)
__global__ void k_pool(const u16* __restrict__ xb, float* __restrict__ g) {
  const int tid = threadIdx.x;
  if (tid >= FEAT) return;
  float s = 0.f;
  const int n0 = blockIdx.x * 100;
  for (int i = 0; i < 100; ++i) s += bu2f(xb[(size_t)(n0 + i) * XPAD + tid]);
  atomicAdd(&g[tid], s);
}

// ---------------------------------------------------------------- NTN bilinear
__global__ __launch_bounds__(256) void k_ntn(const float* __restrict__ W,
                                             const float* __restrict__ g1,
                                             const float* __restrict__ g2,
                                             float* __restrict__ tp) {
  __shared__ float g2s[FEAT];
  const int i = blockIdx.x;
  const int tid = threadIdx.x;
  if (tid < FEAT) g2s[tid] = g2[tid];
  __syncthreads();
  if (tid < NTN_OUT) {
    const float g1i = g1[i];
    float acc = 0.f;
    const float* wr = W + (size_t)i * FEAT * NTN_OUT + tid;
    for (int jj = 0; jj < FEAT; ++jj) acc += wr[(size_t)jj * NTN_OUT] * g2s[jj];
    atomicAdd(&tp[tid], g1i * acc);
  }
}

// ---------------------------------------------------------------- head
__global__ __launch_bounds__(256) void k_feat(
    const float* __restrict__ tp, const float* __restrict__ gv,
    const float* __restrict__ V, const float* __restrict__ B,
    const float* __restrict__ emb, const int* __restrict__ topidx,
    float* __restrict__ featOut) {
  const int tid = threadIdx.x;
  if (tid < NTN_OUT) {
    float acc = B[tid] + tp[tid];
    const float* vr = V + (size_t)tid * 200;
    for (int k = 0; k < 200; ++k) acc += vr[k] * gv[k];
    featOut[tid] = acc > 0.f ? acc : 0.f;
  }
  for (int i = tid; i < RULE_NUMS * FEAT; i += 256) {
    const int rr = i / FEAT;
    const int cc = i - rr * FEAT;
    featOut[NTN_OUT + i] = emb[(size_t)topidx[rr] * FEAT + cc];
  }
}

__global__ __launch_bounds__(256) void k_fc1(
    const float* __restrict__ feat, const float* __restrict__ W,
    const float* __restrict__ b, float* __restrict__ z1) {
  __shared__ __align__(16) float fs[NTN_OUT + RULE_NUMS * FEAT];
  const int tid = threadIdx.x;
  for (int i = tid; i < 450; i += 256) ((float4*)fs)[i] = ((const float4*)feat)[i];
  __syncthreads();
  const int lane = tid & 63;
  const int wv = tid >> 6;
  const int o = blockIdx.x * 4 + wv;
  float acc = 0.f;
  const float4* w4 = (const float4*)(W + (size_t)o * 1800);
  const float4* f4 = (const float4*)fs;
  for (int k = lane; k < 450; k += 64) {
    const float4 a = w4[k], x = f4[k];
    acc += a.x * x.x + a.y * x.y + a.z * x.z + a.w * x.w;
  }
#pragma unroll
  for (int d = 32; d; d >>= 1) acc += __shfl_down(acc, d);
  if (lane == 0) {
    acc += b[o];
    z1[o] = acc > 0.f ? acc : 0.f;
  }
}

__global__ __launch_bounds__(128) void k_head2(
    const float* __restrict__ z1g, const float* __restrict__ fc2W,
    const float* __restrict__ fc2b, const float* __restrict__ fc3W,
    const float* __restrict__ fc3b, float* __restrict__ out) {
  __shared__ __align__(16) float z1[500];
  __shared__ float z2[FEAT];
  const int tid = threadIdx.x;
  for (int i = tid; i < 125; i += 128) ((float4*)z1)[i] = ((const float4*)z1g)[i];
  __syncthreads();
  if (tid < FEAT) {
    float acc = fc2b[tid];
    const float4* w4 = (const float4*)(fc2W + (size_t)tid * 500);
    const float4* f4 = (const float4*)z1;
#pragma unroll 5
    for (int k = 0; k < 125; ++k) {
      const float4 a = w4[k], x = f4[k];
      acc += a.x * x.x + a.y * x.y + a.z * x.z + a.w * x.w;
    }
    z2[tid] = acc > 0.f ? acc : 0.f;
  }
  __syncthreads();
  if (tid == 0) {
    float acc = fc3b[0];
    for (int k = 0; k < FEAT; ++k) acc += fc3W[k] * z2[k];
    out[0] = 1.f / (1.f + expf(-acc));
  }
}

// ================================================================ launch
extern "C" void kernel_launch(void* const* d_in, const int* in_sizes, int n_in,
                              void* d_out, int out_size, void* d_ws, size_t ws_size,
                              hipStream_t stream) {
  (void)in_sizes; (void)n_in; (void)out_size; (void)ws_size;

  const float* nf[2] = {(const float*)d_in[0], (const float*)d_in[1]};
  const int* ei[2] = {(const int*)d_in[2], (const int*)d_in[3]};
  const float* ef[2] = {(const float*)d_in[4], (const float*)d_in[5]};
  const float* rules = (const float*)d_in[6];
  const float* cw[2][6];
  for (int l = 0; l < 2; ++l)
    for (int k = 0; k < 6; ++k) cw[l][k] = (const float*)d_in[7 + l * 6 + k];
  const float* ntnW = (const float*)d_in[19];
  const float* ntnV = (const float*)d_in[20];
  const float* ntnB = (const float*)d_in[21];
  const float* r0Wih = (const float*)d_in[22];
  const float* r0Whh = (const float*)d_in[23];
  const float* r0bih = (const float*)d_in[24];
  const float* r0bhh = (const float*)d_in[25];
  const float* r1Wih = (const float*)d_in[26];
  const float* r1Whh = (const float*)d_in[27];
  const float* r1bih = (const float*)d_in[28];
  const float* r1bhh = (const float*)d_in[29];
  const float* rlW = (const float*)d_in[30];
  const float* rlb = (const float*)d_in[31];
  const float* rkW1 = (const float*)d_in[32];
  const float* rkb1 = (const float*)d_in[33];
  const float* rkW2 = (const float*)d_in[34];
  const float* rkb2 = (const float*)d_in[35];
  const float* rkW3 = (const float*)d_in[36];
  const float* rkb3 = (const float*)d_in[37];
  const float* fc1W = (const float*)d_in[38];
  const float* fc1b = (const float*)d_in[39];
  const float* fc2W = (const float*)d_in[40];
  const float* fc2b = (const float*)d_in[41];
  const float* fc3W = (const float*)d_in[42];
  const float* fc3b = (const float*)d_in[43];

  // ---- workspace layout (~55 MB)
  char* base = (char*)d_ws;
  size_t woff = 0;
#define WS_ALLOC(T, NAME, BYTES) \
  T* NAME = (T*)(base + woff);   \
  woff = (woff + (size_t)(BYTES) + 255) & ~(size_t)255;
  WS_ALLOC(char, rnn_buf, (size_t)5242880)          // RNN/head overlay
  WS_ALLOC(u16, xb0, (size_t)N_NODES * XPAD * 2)
  WS_ALLOC(u16, xb1, (size_t)N_NODES * XPAD * 2)
  WS_ALLOC(u16, Pbuf0, (size_t)N_NODES * XPAD * 2)
  WS_ALLOC(u16, Qbuf0, (size_t)N_NODES * XPAD * 2)
  WS_ALLOC(u16, Pbuf1, (size_t)N_NODES * XPAD * 2)
  WS_ALLOC(u16, Qbuf1, (size_t)N_NODES * XPAD * 2)
  WS_ALLOC(u16, aggb0, (size_t)N_NODES * XPAD * 2)
  WS_ALLOC(u16, aggb1, (size_t)N_NODES * XPAD * 2)
  WS_ALLOC(u16, Wb0, (size_t)3 * 128 * 128 * 2)
  WS_ALLOC(u16, Wb1, (size_t)3 * 128 * 128 * 2)
  WS_ALLOC(u16, Wm, (size_t)4 * 128 * 128 * 2)      // [layer][W1,W2]
  WS_ALLOC(int, offAll, (size_t)2 * (N_NODES + 1) * 4)
  WS_ALLOC(int, cursor, (size_t)2 * N_NODES * 4)
  WS_ALLOC(int, bsum, (size_t)2 * SCAN_B * 4)
  WS_ALLOC(int, el0, (size_t)N_EDGES * 4)
  WS_ALLOC(int, el1, (size_t)N_EDGES * 4)
  WS_ALLOC(int, sp0, (size_t)N_EDGES * 4)
  WS_ALLOC(int, sp1, (size_t)N_EDGES * 4)
  WS_ALLOC(int, dp0, (size_t)N_EDGES * 4)
  WS_ALLOC(int, dp1, (size_t)N_EDGES * 4)
  WS_ALLOC(float, emb, (size_t)N_RULES * FEAT * 4)
  WS_ALLOC(float, scores, (size_t)N_RULES * 4)
  WS_ALLOC(int, topidx, (size_t)RULE_NUMS * 4)
  WS_ALLOC(float, gtp, (size_t)(2 * FEAT + NTN_OUT) * 4)
#undef WS_ALLOC
  u16* xb[2] = {xb0, xb1};
  u16* Wbl[2] = {Wb0, Wb1};
  float* gv = gtp;           // g1[100], g2[100]
  float* tp = gtp + 200;     // tp[200]

  // RNN / head scratch inside rnn_buf (serial stream, disjoint lifetimes)
  float* U   = (float*)rnn_buf;                          // [50][256][64] f32
  u16*   ys  = (u16*)(rnn_buf + 3276800);                // [3200][256] bf16
  float* hT  = (float*)(rnn_buf + 4915200);              // [64][256] f32
  float* featWS = (float*)(rnn_buf + 4980736);
  float* z1WS   = (float*)(rnn_buf + 4988160);

  hipMemsetAsync(cursor, 0, (size_t)2 * N_NODES * 4, stream);
  hipMemsetAsync(gtp, 0, (size_t)(2 * FEAT + NTN_OUT) * 4, stream);

  k_prep<<<2048, 256, 0, stream>>>(nf[0], nf[1], xb[0], xb[1]);
  k_wprep<<<192, 256, 0, stream>>>(cw[0][0], Wb0);
  k_wprep<<<192, 256, 0, stream>>>(cw[1][0], Wb1);
  k_wprep_sq<<<64, 256, 0, stream>>>(cw[0][2], Wm);                 // l0 W1
  k_wprep_sq<<<64, 256, 0, stream>>>(cw[0][4], Wm + 16384);         // l0 W2
  k_wprep_sq<<<64, 256, 0, stream>>>(cw[1][2], Wm + 2 * 16384);     // l1 W1
  k_wprep_sq<<<64, 256, 0, stream>>>(cw[1][4], Wm + 3 * 16384);     // l1 W2

  // ---- CSR both graphs
  const int* src0 = ei[0];
  const int* src1 = ei[1];
  const int* dst0 = ei[0] + N_EDGES;
  const int* dst1 = ei[1] + N_EDGES;
  k_count2<<<dim3(1250, 2), 256, 0, stream>>>(dst0, dst1, cursor);
  k_scan1<<<dim3(SCAN_B, 2), 256, 0, stream>>>(cursor, offAll, bsum);
  k_scan2<<<dim3(1, 2), 128, 0, stream>>>(bsum);
  k_scan3<<<dim3(SCAN_B, 2), 256, 0, stream>>>(bsum, offAll, cursor);
  k_scatter2<<<dim3(1250, 2), 256, 0, stream>>>(src0, dst0, src1, dst1, cursor,
                                                el0, el1, sp0, sp1, dp0, dp1);

  // ---- rule embedding (rnn_buf overlay; finishes before GNN phase)
  {
    dim3 gg(50, 2);
    k_gemm_u<0><<<gg, 256, 0, stream>>>(rules, nullptr, r0Wih, r0bih, r0bhh, U);
    k_rec<1><<<4, 512, 0, stream>>>(U, r0Whh, ys, nullptr);
    k_gemm_u<1><<<gg, 256, 0, stream>>>(nullptr, ys, r1Wih, r1bih, r1bhh, U);
    k_rec<0><<<4, 512, 0, stream>>>(U, r1Whh, nullptr, hT);
    k_rulelin<<<N_RULES, 128, 0, stream>>>(hT, rlW, rlb, emb);
  }
  k_ranker<<<N_RULES, 128, 0, stream>>>(emb, rkW1, rkb1, rkW2, rkb2, rkW3, rkb3,
                                        scores);
  k_topk<<<1, 64, 0, stream>>>(scores, topidx);

  // ---- GNN: 2 TripleConv layers, BOTH graphs per dispatch
  for (int l = 0; l < 2; ++l) {
    k_nodegemm<<<dim3(157, 2, 2), 256, 0, stream>>>(xb0, xb1, Wbl[l], cw[l][1],
                                                    Pbuf0, Qbuf0, Pbuf1, Qbuf1);
    k_msgagg2<<<dim3(N_NODES / NPB, 2), 256, 0, stream>>>(
        ef[0], ef[1], Wbl[l], el0, el1, sp0, sp1, dp0, dp1, offAll,
        Pbuf0, Qbuf0, Pbuf1, Qbuf1, xb0, xb1, aggb0, aggb1);
    k_mlp<<<dim3(157, 2), 256, 0, stream>>>(aggb0, aggb1,
                                            Wm + (size_t)(2 * l) * 16384, cw[l][3],
                                            Wm + (size_t)(2 * l + 1) * 16384,
                                            cw[l][5], xb0, xb1);
  }
  k_pool<<<200, 128, 0, stream>>>(xb0, gv);
  k_pool<<<200, 128, 0, stream>>>(xb1, gv + FEAT);

  // ---- NTN + head
  k_ntn<<<FEAT, 256, 0, stream>>>(ntnW, gv, gv + FEAT, tp);
  k_feat<<<1, 256, 0, stream>>>(tp, gv, ntnV, ntnB, emb, topidx, featWS);
  k_fc1<<<125, 256, 0, stream>>>(featWS, fc1W, fc1b, z1WS);
  k_head2<<<1, 128, 0, stream>>>(z1WS, fc2W, fc2b, fc3W, fc3b, (float*)d_out);
}